// Round 1
// baseline (1280.867 us; speedup 1.0000x reference)
//
#include <hip/hip_runtime.h>

typedef unsigned short ushort_t;
typedef __attribute__((ext_vector_type(8))) short short8;
typedef __attribute__((ext_vector_type(4))) float f32x4;

#define AS1U(p) ((const __attribute__((address_space(1))) unsigned int*)(p))
#define AS3U(p) ((__attribute__((address_space(3))) unsigned int*)(p))

__device__ __forceinline__ float bf2f(ushort_t u) {
  union { unsigned int i; float f; } v; v.i = ((unsigned int)u) << 16; return v.f;
}
__device__ __forceinline__ ushort_t f2bf(float f) {
  union { float f; unsigned int i; } v; v.f = f;
  unsigned int r = v.i + 0x7fffu + ((v.i >> 16) & 1u);
  return (ushort_t)(r >> 16);
}

// -------------------- f32 -> bf16 (8 elems/thread) --------------------
__global__ void cvt_bf16(const float* __restrict__ src, ushort_t* __restrict__ dst, int n8) {
  int i = blockIdx.x * 256 + threadIdx.x;
  if (i >= n8) return;
  const float4* s4 = (const float4*)src;
  float4 a = s4[2 * i], b = s4[2 * i + 1];
  short8 u;
  u[0] = (short)f2bf(a.x); u[1] = (short)f2bf(a.y); u[2] = (short)f2bf(a.z); u[3] = (short)f2bf(a.w);
  u[4] = (short)f2bf(b.x); u[5] = (short)f2bf(b.y); u[6] = (short)f2bf(b.z); u[7] = (short)f2bf(b.w);
  *(short8*)(dst + (size_t)i * 8) = u;
}

// -------------------- bf16 GEMM: C[M][N] = A[M][K] * B[N][K]^T --------------------
// 128x128 tile, BK=32, 4 waves (2x2), each wave 64x64 (4x4 frags of 16x16x32).
template <int OUTF32>
__global__ __launch_bounds__(256) void gemm_bt(const ushort_t* __restrict__ A,
                                               const ushort_t* __restrict__ B,
                                               void* __restrict__ Cv,
                                               int M, int N, int K) {
  __shared__ __align__(16) ushort_t As[128 * 32];
  __shared__ __align__(16) ushort_t Bs[128 * 32];
  const int t = threadIdx.x;
  const int lane = t & 63, w = t >> 6;
  const int wr = w >> 1, wc = w & 1;
  const int r = lane & 15, g = lane >> 4;
  const int m0 = blockIdx.x * 128, n0 = blockIdx.y * 128;
  f32x4 acc[4][4] = {};
  for (int k0 = 0; k0 < K; k0 += 32) {
    __syncthreads();
#pragma unroll
    for (int i = 0; i < 2; ++i) {
      int slot = t + i * 256;          // 16B slots, 512 per tile
      int row = slot >> 2;             // 64B per row (32 bf16)
      int c8 = (slot & 3) * 8;         // elem offset in row
      __builtin_amdgcn_global_load_lds(AS1U(A + (size_t)(m0 + row) * K + k0 + c8),
                                       AS3U(As + slot * 8), 16, 0, 0);
      __builtin_amdgcn_global_load_lds(AS1U(B + (size_t)(n0 + row) * K + k0 + c8),
                                       AS3U(Bs + slot * 8), 16, 0, 0);
    }
    __syncthreads();
    short8 afrag[4], bfrag[4];
#pragma unroll
    for (int m = 0; m < 4; ++m)
      afrag[m] = *(const short8*)(As + (wr * 64 + m * 16 + r) * 32 + g * 8);
#pragma unroll
    for (int n = 0; n < 4; ++n)
      bfrag[n] = *(const short8*)(Bs + (wc * 64 + n * 16 + r) * 32 + g * 8);
#pragma unroll
    for (int m = 0; m < 4; ++m)
#pragma unroll
      for (int n = 0; n < 4; ++n)
        acc[m][n] = __builtin_amdgcn_mfma_f32_16x16x32_bf16(afrag[m], bfrag[n], acc[m][n], 0, 0, 0);
  }
#pragma unroll
  for (int m = 0; m < 4; ++m)
#pragma unroll
    for (int n = 0; n < 4; ++n)
#pragma unroll
      for (int j = 0; j < 4; ++j) {
        int row = m0 + wr * 64 + m * 16 + g * 4 + j;
        int col = n0 + wc * 64 + n * 16 + r;
        if (OUTF32)
          ((float*)Cv)[(size_t)row * N + col] = acc[m][n][j];
        else
          ((ushort_t*)Cv)[(size_t)row * N + col] = f2bf(acc[m][n][j]);
      }
}

// -------------------- fused RMSNorm + RoPE + head split --------------------
// grid (80, 2048), block 64 (1 wave). slot 0..63 = q heads, 64..71 = k heads, 72..79 = v copy.
__global__ void normrope(const ushort_t* __restrict__ qkv,
                         const float* __restrict__ qw, const float* __restrict__ kw,
                         const float* __restrict__ fc, const float* __restrict__ fs,
                         ushort_t* __restrict__ Qb, ushort_t* __restrict__ Kb,
                         ushort_t* __restrict__ Vb) {
  const int slot = blockIdx.x, s = blockIdx.y, t = threadIdx.x;
  const ushort_t* src;
  ushort_t* dst;
  const float* wn;
  float scale = 1.0f;
  if (slot < 64) {
    src = qkv + (size_t)s * 10240 + slot * 128;
    dst = Qb + ((size_t)slot * 2048 + s) * 128;
    wn = qw;
    scale = 0.08838834764831845f;  // 1/sqrt(128) folded into Q
  } else if (slot < 72) {
    int kh = slot - 64;
    src = qkv + (size_t)s * 10240 + 8192 + kh * 128;
    dst = Kb + ((size_t)kh * 2048 + s) * 128;
    wn = kw;
  } else {
    int kh = slot - 72;
    src = qkv + (size_t)s * 10240 + 9216 + kh * 128;
    dst = Vb + ((size_t)kh * 2048 + s) * 128;
    dst[2 * t] = src[2 * t];
    dst[2 * t + 1] = src[2 * t + 1];
    return;
  }
  float e0 = bf2f(src[2 * t]), e1 = bf2f(src[2 * t + 1]);
  float ss = e0 * e0 + e1 * e1;
#pragma unroll
  for (int m = 1; m < 64; m <<= 1) ss += __shfl_xor(ss, m);
  float rn = rsqrtf(ss * (1.0f / 128.0f) + 1e-6f);
  float v0 = e0 * rn * wn[2 * t], v1 = e1 * rn * wn[2 * t + 1];
  float c = fc[s * 64 + t], sn = fs[s * 64 + t];
  float oe = v0 * c - v1 * sn;
  float oo = v0 * sn + v1 * c;
  dst[2 * t] = f2bf(oe * scale);
  dst[2 * t + 1] = f2bf(oo * scale);
}

// -------------------- causal flash attention (GQA 8:1) --------------------
// grid (16 qtiles, 64 heads), block 256 (4 waves). Wave w: 32 q-rows. KV tile 64.
__global__ __launch_bounds__(256) void attn_fwd(const ushort_t* __restrict__ Qg,
                                                const ushort_t* __restrict__ Kg,
                                                const ushort_t* __restrict__ Vg,
                                                ushort_t* __restrict__ Og) {
  __shared__ __align__(16) ushort_t Ks[64 * 128];      // [kvpos][d], XOR-swizzled
  __shared__ __align__(16) ushort_t Vt[128 * 64];      // [d][kvpos], XOR-swizzled
  __shared__ __align__(16) ushort_t Ps[4][32 * 64];    // per-wave P, XOR-swizzled
  const int t = threadIdx.x, lane = t & 63, w = t >> 6;
  const int r = lane & 15, g = lane >> 4;
  const int qt = blockIdx.x, h = blockIdx.y, kvh = h >> 3;
  const int qrow0 = qt * 128 + w * 32;

  short8 qf[2][4];
#pragma unroll
  for (int qr = 0; qr < 2; ++qr)
#pragma unroll
    for (int kk = 0; kk < 4; ++kk)
      qf[qr][kk] = *(const short8*)(Qg + ((size_t)h * 2048 + qrow0 + qr * 16 + r) * 128 + kk * 32 + g * 8);

  f32x4 o[2][8] = {};
  float mrun[2][4], lrun[2][4];
#pragma unroll
  for (int qr = 0; qr < 2; ++qr)
#pragma unroll
    for (int j = 0; j < 4; ++j) { mrun[qr][j] = -3.0e38f; lrun[qr][j] = 0.0f; }

  const int kbmax = (qt * 128 + 127) >> 6;
  for (int kb = 0; kb <= kbmax; ++kb) {
    __syncthreads();
    // stage K (swizzled row-major) and V^T (swizzled) into LDS
#pragma unroll
    for (int i = 0; i < 4; ++i) {
      int s8 = t + i * 256;  // 1024 vec8 slots
      int krow = s8 >> 4, c8 = s8 & 15;
      const size_t gb = ((size_t)kvh * 2048 + kb * 64 + krow) * 128 + c8 * 8;
      short8 kv = *(const short8*)(Kg + gb);
      *(short8*)((char*)Ks + ((s8 * 16) ^ ((krow & 7) << 4))) = kv;
      short8 vv = *(const short8*)(Vg + gb);
#pragma unroll
      for (int j = 0; j < 8; ++j) {
        int d = c8 * 8 + j;
        *(ushort_t*)((char*)Vt + ((d * 128 + krow * 2) ^ ((d & 7) << 4))) = (ushort_t)vv[j];
      }
    }
    __syncthreads();

    // S = Q K^T (pre-scaled Q)
    f32x4 s[2][4] = {};
#pragma unroll
    for (int kk = 0; kk < 4; ++kk) {
      short8 kf[4];
#pragma unroll
      for (int nc = 0; nc < 4; ++nc) {
        int n = nc * 16 + r;
        kf[nc] = *(const short8*)((char*)Ks + (n * 256 + (((kk * 64 + g * 16)) ^ ((n & 7) << 4))));
      }
#pragma unroll
      for (int qr = 0; qr < 2; ++qr)
#pragma unroll
        for (int nc = 0; nc < 4; ++nc)
          s[qr][nc] = __builtin_amdgcn_mfma_f32_16x16x32_bf16(qf[qr][kk], kf[nc], s[qr][nc], 0, 0, 0);
    }

    // causal mask + online softmax (rows live in 16-lane groups)
#pragma unroll
    for (int qr = 0; qr < 2; ++qr)
#pragma unroll
      for (int j = 0; j < 4; ++j) {
        int grow = qrow0 + qr * 16 + g * 4 + j;
        float mx = -3.0e38f;
#pragma unroll
        for (int nc = 0; nc < 4; ++nc) {
          int gcol = kb * 64 + nc * 16 + r;
          if (gcol > grow) s[qr][nc][j] = -1e30f;
          mx = fmaxf(mx, s[qr][nc][j]);
        }
        mx = fmaxf(mx, __shfl_xor(mx, 1));
        mx = fmaxf(mx, __shfl_xor(mx, 2));
        mx = fmaxf(mx, __shfl_xor(mx, 4));
        mx = fmaxf(mx, __shfl_xor(mx, 8));
        float mn = fmaxf(mrun[qr][j], mx);
        float sc = __expf(mrun[qr][j] - mn);
        mrun[qr][j] = mn;
        float rs = 0.0f;
#pragma unroll
        for (int nc = 0; nc < 4; ++nc) {
          float p = __expf(s[qr][nc][j] - mn);
          s[qr][nc][j] = p;
          rs += p;
        }
        rs += __shfl_xor(rs, 1);
        rs += __shfl_xor(rs, 2);
        rs += __shfl_xor(rs, 4);
        rs += __shfl_xor(rs, 8);
        lrun[qr][j] = lrun[qr][j] * sc + rs;
#pragma unroll
        for (int dc = 0; dc < 8; ++dc) o[qr][dc][j] *= sc;
      }

    // P (bf16) -> per-wave LDS (swizzled), then PV
#pragma unroll
    for (int qr = 0; qr < 2; ++qr)
#pragma unroll
      for (int nc = 0; nc < 4; ++nc)
#pragma unroll
        for (int j = 0; j < 4; ++j) {
          int prow = qr * 16 + g * 4 + j;
          int colb = (nc * 16 + r) * 2;
          *(ushort_t*)((char*)Ps[w] + (prow * 128 + (colb ^ ((prow & 7) << 4)))) = f2bf(s[qr][nc][j]);
        }
    asm volatile("s_waitcnt lgkmcnt(0)" ::: "memory");
#pragma unroll
    for (int ks = 0; ks < 2; ++ks) {
      short8 pf[2];
#pragma unroll
      for (int qr = 0; qr < 2; ++qr) {
        int prow = qr * 16 + r;
        pf[qr] = *(const short8*)((char*)Ps[w] + (prow * 128 + ((ks * 64 + g * 16) ^ ((prow & 7) << 4))));
      }
#pragma unroll
      for (int dc = 0; dc < 8; ++dc) {
        int dd = dc * 16 + r;
        short8 vf = *(const short8*)((char*)Vt + (dd * 128 + ((ks * 64 + g * 16) ^ ((dd & 7) << 4))));
#pragma unroll
        for (int qr = 0; qr < 2; ++qr)
          o[qr][dc] = __builtin_amdgcn_mfma_f32_16x16x32_bf16(pf[qr], vf, o[qr][dc], 0, 0, 0);
      }
    }
  }

  // normalize + store: attnb[s][h*128+d]
#pragma unroll
  for (int qr = 0; qr < 2; ++qr)
#pragma unroll
    for (int dc = 0; dc < 8; ++dc)
#pragma unroll
      for (int j = 0; j < 4; ++j) {
        int row = qrow0 + qr * 16 + g * 4 + j;
        int col = dc * 16 + r;
        Og[(size_t)row * 8192 + h * 128 + col] = f2bf(o[qr][dc][j] / lrun[qr][j]);
      }
}

// -------------------- host --------------------
extern "C" void kernel_launch(void* const* d_in, const int* in_sizes, int n_in,
                              void* d_out, int out_size, void* d_ws, size_t ws_size,
                              hipStream_t stream) {
  const float* x = (const float*)d_in[0];
  const float* wq = (const float*)d_in[1];
  const float* wk = (const float*)d_in[2];
  const float* wv = (const float*)d_in[3];
  const float* wo = (const float*)d_in[4];
  const float* qw = (const float*)d_in[5];
  const float* kw = (const float*)d_in[6];
  const float* fc = (const float*)d_in[9];
  const float* fs = (const float*)d_in[10];

  char* ws = (char*)d_ws;
  // layout (aliased, sequential-use):
  //   [0, 104857600)            Wb: packed wqkv bf16 (10240x5120); later wo bf16 (5120x8192)
  //   [104857600, 146800640)    qkv bf16 (2048x10240); later attnb bf16 (2048x8192)
  //   [146800640, 180355072)    xb bf16 (2048x5120); later Q bf16 (64x2048x128)
  //   [180355072, 184549376)    K bf16 (8x2048x128)
  //   [184549376, 188743680)    V bf16 (8x2048x128)
  ushort_t* Wb = (ushort_t*)(ws);
  ushort_t* qkv = (ushort_t*)(ws + 104857600);
  ushort_t* xb = (ushort_t*)(ws + 146800640);
  ushort_t* Qb = xb;
  ushort_t* Kb = (ushort_t*)(ws + 180355072);
  ushort_t* Vb = (ushort_t*)(ws + 184549376);
  ushort_t* attnb = qkv;

  {
    int n8 = 2048 * 5120 / 8;
    cvt_bf16<<<dim3((n8 + 255) / 256), 256, 0, stream>>>(x, xb, n8);
  }
  {
    int n8 = 8192 * 5120 / 8;
    cvt_bf16<<<dim3((n8 + 255) / 256), 256, 0, stream>>>(wq, Wb, n8);
  }
  {
    int n8 = 1024 * 5120 / 8;
    cvt_bf16<<<dim3((n8 + 255) / 256), 256, 0, stream>>>(wk, Wb + (size_t)8192 * 5120, n8);
    cvt_bf16<<<dim3((n8 + 255) / 256), 256, 0, stream>>>(wv, Wb + (size_t)9216 * 5120, n8);
  }

  // qkv = x @ [wq;wk;wv]^T   (2048 x 10240 x 5120)
  gemm_bt<0><<<dim3(16, 80), 256, 0, stream>>>(xb, Wb, qkv, 2048, 10240, 5120);

  // convert wo (reuses Wb region; stream-ordered after gemm above)
  {
    int n8 = 5120 * 8192 / 8;
    cvt_bf16<<<dim3((n8 + 255) / 256), 256, 0, stream>>>(wo, Wb, n8);
  }

  // rmsnorm + rope + split into head-major Q/K/V
  normrope<<<dim3(80, 2048), 64, 0, stream>>>(qkv, qw, kw, fc, fs, Qb, Kb, Vb);

  // causal flash attention
  attn_fwd<<<dim3(16, 64), 256, 0, stream>>>(Qb, Kb, Vb, attnb);

  // out = attn @ wo^T  (2048 x 5120 x 8192), f32 output
  gemm_bt<1><<<dim3(16, 40), 256, 0, stream>>>(attnb, Wb, (float*)d_out, 2048, 5120, 8192);
}

// Round 3
// 974.204 us; speedup vs baseline: 1.3148x; 1.3148x over previous
//
#include <hip/hip_runtime.h>

typedef unsigned short ushort_t;
typedef __attribute__((ext_vector_type(8))) short short8;
typedef __attribute__((ext_vector_type(4))) float f32x4;

#define AS1U(p) ((const __attribute__((address_space(1))) unsigned int*)(p))
#define AS3U(p) ((__attribute__((address_space(3))) unsigned int*)(p))

__device__ __forceinline__ float bf2f(ushort_t u) {
  union { unsigned int i; float f; } v; v.i = ((unsigned int)u) << 16; return v.f;
}
__device__ __forceinline__ ushort_t f2bf(float f) {
  union { float f; unsigned int i; } v; v.f = f;
  unsigned int r = v.i + 0x7fffu + ((v.i >> 16) & 1u);
  return (ushort_t)(r >> 16);
}

// -------------------- f32 -> bf16 (8 elems/thread) --------------------
__global__ void cvt_bf16(const float* __restrict__ src, ushort_t* __restrict__ dst, int n8) {
  int i = blockIdx.x * 256 + threadIdx.x;
  if (i >= n8) return;
  const float4* s4 = (const float4*)src;
  float4 a = s4[2 * i], b = s4[2 * i + 1];
  short8 u;
  u[0] = (short)f2bf(a.x); u[1] = (short)f2bf(a.y); u[2] = (short)f2bf(a.z); u[3] = (short)f2bf(a.w);
  u[4] = (short)f2bf(b.x); u[5] = (short)f2bf(b.y); u[6] = (short)f2bf(b.z); u[7] = (short)f2bf(b.w);
  *(short8*)(dst + (size_t)i * 8) = u;
}

// -------------------- bf16 GEMM: C[M][N] = A[M][K] * B[N][K]^T --------------------
// 128x128 tile, BK=32, 4 waves (2x2), each wave 64x64 (4x4 frags of 16x16x32).
// gridDim.x must be a power of two; gridDim.x*gridDim.y must be a multiple of 8.
template <int OUTF32>
__global__ __launch_bounds__(256) void gemm_bt(const ushort_t* __restrict__ A,
                                               const ushort_t* __restrict__ B,
                                               void* __restrict__ Cv,
                                               int M, int N, int K) {
  __shared__ __align__(16) ushort_t As[128 * 32];
  __shared__ __align__(16) ushort_t Bs[128 * 32];
  const int t = threadIdx.x;
  const int lane = t & 63, w = t >> 6;
  const int wr = w >> 1, wc = w & 1;
  const int r = lane & 15, g = lane >> 4;
  // XCD-aware bijective swizzle (nwg % 8 == 0)
  const int nwg = gridDim.x * gridDim.y;
  const int l = blockIdx.y * gridDim.x + blockIdx.x;
  const int wg = (l & 7) * (nwg >> 3) + (l >> 3);
  const int m0 = (wg & (gridDim.x - 1)) * 128, n0 = (wg / gridDim.x) * 128;
  f32x4 acc[4][4] = {};
  for (int k0 = 0; k0 < K; k0 += 32) {
    __syncthreads();
#pragma unroll
    for (int i = 0; i < 2; ++i) {
      int slot = t + i * 256;          // 16B slots, 512 per tile
      int row = slot >> 2;             // 64B per row (32 bf16)
      int c8 = (slot & 3) * 8;         // elem offset in row
      __builtin_amdgcn_global_load_lds(AS1U(A + (size_t)(m0 + row) * K + k0 + c8),
                                       AS3U(As + slot * 8), 16, 0, 0);
      __builtin_amdgcn_global_load_lds(AS1U(B + (size_t)(n0 + row) * K + k0 + c8),
                                       AS3U(Bs + slot * 8), 16, 0, 0);
    }
    __syncthreads();
    short8 afrag[4], bfrag[4];
#pragma unroll
    for (int m = 0; m < 4; ++m)
      afrag[m] = *(const short8*)(As + (wr * 64 + m * 16 + r) * 32 + g * 8);
#pragma unroll
    for (int n = 0; n < 4; ++n)
      bfrag[n] = *(const short8*)(Bs + (wc * 64 + n * 16 + r) * 32 + g * 8);
    __builtin_amdgcn_s_setprio(1);
#pragma unroll
    for (int m = 0; m < 4; ++m)
#pragma unroll
      for (int n = 0; n < 4; ++n)
        acc[m][n] = __builtin_amdgcn_mfma_f32_16x16x32_bf16(afrag[m], bfrag[n], acc[m][n], 0, 0, 0);
    __builtin_amdgcn_s_setprio(0);
  }
#pragma unroll
  for (int m = 0; m < 4; ++m)
#pragma unroll
    for (int n = 0; n < 4; ++n)
#pragma unroll
      for (int j = 0; j < 4; ++j) {
        int row = m0 + wr * 64 + m * 16 + g * 4 + j;
        int col = n0 + wc * 64 + n * 16 + r;
        if (OUTF32)
          ((float*)Cv)[(size_t)row * N + col] = acc[m][n][j];
        else
          ((ushort_t*)Cv)[(size_t)row * N + col] = f2bf(acc[m][n][j]);
      }
}

// -------------------- fused RMSNorm + RoPE + head split --------------------
// grid (72, 2048), block 64 (1 wave). slot 0..63 = q heads, 64..71 = k heads.
__global__ void normrope(const ushort_t* __restrict__ qkv,
                         const float* __restrict__ qw, const float* __restrict__ kw,
                         const float* __restrict__ fc, const float* __restrict__ fs,
                         ushort_t* __restrict__ Qb, ushort_t* __restrict__ Kb) {
  const int slot = blockIdx.x, s = blockIdx.y, t = threadIdx.x;
  const ushort_t* src;
  ushort_t* dst;
  const float* wn;
  float scale = 1.0f;
  if (slot < 64) {
    src = qkv + (size_t)s * 10240 + slot * 128;
    dst = Qb + ((size_t)slot * 2048 + s) * 128;
    wn = qw;
    scale = 0.08838834764831845f;  // 1/sqrt(128) folded into Q
  } else {
    int kh = slot - 64;
    src = qkv + (size_t)s * 10240 + 8192 + kh * 128;
    dst = Kb + ((size_t)kh * 2048 + s) * 128;
    wn = kw;
  }
  float e0 = bf2f(src[2 * t]), e1 = bf2f(src[2 * t + 1]);
  float ss = e0 * e0 + e1 * e1;
#pragma unroll
  for (int m = 1; m < 64; m <<= 1) ss += __shfl_xor(ss, m);
  float rn = rsqrtf(ss * (1.0f / 128.0f) + 1e-6f);
  float v0 = e0 * rn * wn[2 * t], v1 = e1 * rn * wn[2 * t + 1];
  float c = fc[s * 64 + t], sn = fs[s * 64 + t];
  float oe = v0 * c - v1 * sn;
  float oo = v0 * sn + v1 * c;
  dst[2 * t] = f2bf(oe * scale);
  dst[2 * t + 1] = f2bf(oo * scale);
}

// -------------------- V transpose: qkv V-section [s][kvh*128+d] -> Vt[kvh][d][s] --------------------
// grid (32 s-tiles, 8 kvh), block 256. LDS tile [64 s][128 d], XOR-swizzled.
__global__ __launch_bounds__(256) void vtrans(const ushort_t* __restrict__ qkv,
                                              ushort_t* __restrict__ Vt) {
  __shared__ __align__(16) ushort_t T[64 * 128];
  const int t = threadIdx.x, st = blockIdx.x, kvh = blockIdx.y;
#pragma unroll
  for (int i = 0; i < 4; ++i) {
    int slot = t + i * 256;          // 1024 vec8 slots
    int srow = slot >> 4, c8 = slot & 15;
    short8 v = *(const short8*)(qkv + (size_t)(st * 64 + srow) * 10240 + 9216 + kvh * 128 + c8 * 8);
    int sw = (((srow & 7) ^ ((srow >> 3) & 7)) << 4);
    *(short8*)((char*)T + srow * 256 + ((c8 * 16) ^ sw)) = v;
  }
  __syncthreads();
#pragma unroll
  for (int i = 0; i < 4; ++i) {
    int slot = t + i * 256;
    int d = slot >> 3, s8 = slot & 7;
    short8 u;
#pragma unroll
    for (int j = 0; j < 8; ++j) {
      int row = s8 * 8 + j;
      int sw = (((row & 7) ^ ((row >> 3) & 7)) << 4);
      u[j] = *(const ushort_t*)((char*)T + row * 256 + ((d * 2) ^ sw));
    }
    *(short8*)(Vt + ((size_t)kvh * 128 + d) * 2048 + st * 64 + s8 * 8) = u;
  }
}

// -------------------- causal flash attention (GQA 8:1) --------------------
// grid (64 heads, 16 qtiles reversed), block 256 (4 waves). Wave w: 32 q-rows. KV tile 64.
__global__ __launch_bounds__(256) void attn_fwd(const ushort_t* __restrict__ Qg,
                                                const ushort_t* __restrict__ Kg,
                                                const ushort_t* __restrict__ VtG,
                                                ushort_t* __restrict__ Og) {
  __shared__ __align__(16) ushort_t Ks[64 * 128];      // [kvpos][d], XOR-swizzled
  __shared__ __align__(16) ushort_t Vs[128 * 64];      // [d][kvpos], XOR-swizzled
  __shared__ __align__(16) ushort_t Ps[4][32 * 64];    // per-wave P, XOR-swizzled
  const int t = threadIdx.x, lane = t & 63, w = t >> 6;
  const int r = lane & 15, g = lane >> 4;
  const int h = blockIdx.x, qt = (int)gridDim.y - 1 - (int)blockIdx.y, kvh = h >> 3;
  const int qrow0 = qt * 128 + w * 32;

  short8 qf[2][4];
#pragma unroll
  for (int qr = 0; qr < 2; ++qr)
#pragma unroll
    for (int kk = 0; kk < 4; ++kk)
      qf[qr][kk] = *(const short8*)(Qg + ((size_t)h * 2048 + qrow0 + qr * 16 + r) * 128 + kk * 32 + g * 8);

  f32x4 o[2][8] = {};
  float mrun[2][4], lrun[2][4];
#pragma unroll
  for (int qr = 0; qr < 2; ++qr)
#pragma unroll
    for (int j = 0; j < 4; ++j) { mrun[qr][j] = -3.0e38f; lrun[qr][j] = 0.0f; }

  // prefetch registers (T14 async-STAGE split)
  short8 kpf[4], vpf[4];
  auto LOADKV = [&](int kb) {
#pragma unroll
    for (int i = 0; i < 4; ++i) {
      int s8 = t + i * 256;  // 1024 vec8 slots each for K and V^T
      int krow = s8 >> 4, kc8 = s8 & 15;
      kpf[i] = *(const short8*)(Kg + ((size_t)kvh * 2048 + kb * 64 + krow) * 128 + kc8 * 8);
      int d = s8 >> 3, vc8 = s8 & 7;
      vpf[i] = *(const short8*)(VtG + ((size_t)kvh * 128 + d) * 2048 + kb * 64 + vc8 * 8);
    }
  };

  const int kbmax = (qt * 128 + 127) >> 6;
  LOADKV(0);
  for (int kb = 0; kb <= kbmax; ++kb) {
    __syncthreads();
    // regs -> LDS (swizzled)
#pragma unroll
    for (int i = 0; i < 4; ++i) {
      int s8 = t + i * 256;
      int krow = s8 >> 4;
      *(short8*)((char*)Ks + ((s8 * 16) ^ ((krow & 7) << 4))) = kpf[i];
      int d = s8 >> 3;
      *(short8*)((char*)Vs + ((s8 * 16) ^ ((d & 7) << 4))) = vpf[i];
    }
    __syncthreads();
    if (kb < kbmax) LOADKV(kb + 1);  // overlap next-tile HBM with compute

    // S = Q K^T (pre-scaled Q)
    f32x4 s[2][4] = {};
#pragma unroll
    for (int kk = 0; kk < 4; ++kk) {
      short8 kf[4];
#pragma unroll
      for (int nc = 0; nc < 4; ++nc) {
        int n = nc * 16 + r;
        kf[nc] = *(const short8*)((char*)Ks + (n * 256 + (((kk * 64 + g * 16)) ^ ((n & 7) << 4))));
      }
      __builtin_amdgcn_s_setprio(1);
#pragma unroll
      for (int qr = 0; qr < 2; ++qr)
#pragma unroll
        for (int nc = 0; nc < 4; ++nc)
          s[qr][nc] = __builtin_amdgcn_mfma_f32_16x16x32_bf16(qf[qr][kk], kf[nc], s[qr][nc], 0, 0, 0);
      __builtin_amdgcn_s_setprio(0);
    }

    // causal mask + online softmax (rows live in 16-lane groups)
#pragma unroll
    for (int qr = 0; qr < 2; ++qr)
#pragma unroll
      for (int j = 0; j < 4; ++j) {
        int grow = qrow0 + qr * 16 + g * 4 + j;
        float mx = -3.0e38f;
#pragma unroll
        for (int nc = 0; nc < 4; ++nc) {
          int gcol = kb * 64 + nc * 16 + r;
          if (gcol > grow) s[qr][nc][j] = -1e30f;
          mx = fmaxf(mx, s[qr][nc][j]);
        }
        mx = fmaxf(mx, __shfl_xor(mx, 1));
        mx = fmaxf(mx, __shfl_xor(mx, 2));
        mx = fmaxf(mx, __shfl_xor(mx, 4));
        mx = fmaxf(mx, __shfl_xor(mx, 8));
        float mn = fmaxf(mrun[qr][j], mx);
        float sc = __expf(mrun[qr][j] - mn);
        mrun[qr][j] = mn;
        float rs = 0.0f;
#pragma unroll
        for (int nc = 0; nc < 4; ++nc) {
          float p = __expf(s[qr][nc][j] - mn);
          s[qr][nc][j] = p;
          rs += p;
        }
        rs += __shfl_xor(rs, 1);
        rs += __shfl_xor(rs, 2);
        rs += __shfl_xor(rs, 4);
        rs += __shfl_xor(rs, 8);
        lrun[qr][j] = lrun[qr][j] * sc + rs;
#pragma unroll
        for (int dc = 0; dc < 8; ++dc) o[qr][dc][j] *= sc;
      }

    // P (bf16) -> per-wave LDS (swizzled), then PV
#pragma unroll
    for (int qr = 0; qr < 2; ++qr)
#pragma unroll
      for (int nc = 0; nc < 4; ++nc)
#pragma unroll
        for (int j = 0; j < 4; ++j) {
          int prow = qr * 16 + g * 4 + j;
          int colb = (nc * 16 + r) * 2;
          *(ushort_t*)((char*)Ps[w] + (prow * 128 + (colb ^ ((prow & 7) << 4)))) = f2bf(s[qr][nc][j]);
        }
    asm volatile("s_waitcnt lgkmcnt(0)" ::: "memory");
#pragma unroll
    for (int ks = 0; ks < 2; ++ks) {
      short8 pf[2];
#pragma unroll
      for (int qr = 0; qr < 2; ++qr) {
        int prow = qr * 16 + r;
        pf[qr] = *(const short8*)((char*)Ps[w] + (prow * 128 + ((ks * 64 + g * 16) ^ ((prow & 7) << 4))));
      }
#pragma unroll
      for (int dc = 0; dc < 8; ++dc) {
        int dd = dc * 16 + r;
        short8 vf = *(const short8*)((char*)Vs + (dd * 128 + ((ks * 64 + g * 16) ^ ((dd & 7) << 4))));
        __builtin_amdgcn_s_setprio(1);
#pragma unroll
        for (int qr = 0; qr < 2; ++qr)
          o[qr][dc] = __builtin_amdgcn_mfma_f32_16x16x32_bf16(pf[qr], vf, o[qr][dc], 0, 0, 0);
        __builtin_amdgcn_s_setprio(0);
      }
    }
  }

  // normalize + store: attnb[s][h*128+d]
#pragma unroll
  for (int qr = 0; qr < 2; ++qr)
#pragma unroll
    for (int dc = 0; dc < 8; ++dc)
#pragma unroll
      for (int j = 0; j < 4; ++j) {
        int row = qrow0 + qr * 16 + g * 4 + j;
        int col = dc * 16 + r;
        Og[(size_t)row * 8192 + h * 128 + col] = f2bf(o[qr][dc][j] / lrun[qr][j]);
      }
}

// -------------------- host --------------------
extern "C" void kernel_launch(void* const* d_in, const int* in_sizes, int n_in,
                              void* d_out, int out_size, void* d_ws, size_t ws_size,
                              hipStream_t stream) {
  const float* x = (const float*)d_in[0];
  const float* wq = (const float*)d_in[1];
  const float* wk = (const float*)d_in[2];
  const float* wv = (const float*)d_in[3];
  const float* wo = (const float*)d_in[4];
  const float* qw = (const float*)d_in[5];
  const float* kw = (const float*)d_in[6];
  const float* fc = (const float*)d_in[9];
  const float* fs = (const float*)d_in[10];

  char* ws = (char*)d_ws;
  // layout (aliased, sequential-use):
  //   [0, 104857600)            Wb: packed wqkv bf16 (10240x5120); later wo bf16 (5120x8192)
  //   [104857600, 146800640)    qkv bf16 (2048x10240); later attnb bf16 (2048x8192)
  //   [146800640, 180355072)    xb bf16 (2048x5120); later Q bf16 (64x2048x128)
  //   [180355072, 184549376)    K bf16 (8x2048x128)
  //   [184549376, 188743680)    Vt bf16 (8x128x2048)
  ushort_t* Wb = (ushort_t*)(ws);
  ushort_t* qkv = (ushort_t*)(ws + 104857600);
  ushort_t* xb = (ushort_t*)(ws + 146800640);
  ushort_t* Qb = xb;
  ushort_t* Kb = (ushort_t*)(ws + 180355072);
  ushort_t* Vtb = (ushort_t*)(ws + 184549376);
  ushort_t* attnb = qkv;

  {
    int n8 = 2048 * 5120 / 8;
    cvt_bf16<<<dim3((n8 + 255) / 256), 256, 0, stream>>>(x, xb, n8);
  }
  {
    int n8 = 8192 * 5120 / 8;
    cvt_bf16<<<dim3((n8 + 255) / 256), 256, 0, stream>>>(wq, Wb, n8);
  }
  {
    int n8 = 1024 * 5120 / 8;
    cvt_bf16<<<dim3((n8 + 255) / 256), 256, 0, stream>>>(wk, Wb + (size_t)8192 * 5120, n8);
    cvt_bf16<<<dim3((n8 + 255) / 256), 256, 0, stream>>>(wv, Wb + (size_t)9216 * 5120, n8);
  }

  // qkv = x @ [wq;wk;wv]^T   (2048 x 10240 x 5120)
  gemm_bt<0><<<dim3(16, 80), 256, 0, stream>>>(xb, Wb, qkv, 2048, 10240, 5120);

  // convert wo (reuses Wb region; stream-ordered after gemm above)
  {
    int n8 = 5120 * 8192 / 8;
    cvt_bf16<<<dim3((n8 + 255) / 256), 256, 0, stream>>>(wo, Wb, n8);
  }

  // rmsnorm + rope + split into head-major Q/K
  normrope<<<dim3(72, 2048), 64, 0, stream>>>(qkv, qw, kw, fc, fs, Qb, Kb);

  // V transpose: [s][kvh][d] -> [kvh][d][s]
  vtrans<<<dim3(32, 8), 256, 0, stream>>>(qkv, Vtb);

  // causal flash attention (heavy q-tiles dispatched first)
  attn_fwd<<<dim3(64, 16), 256, 0, stream>>>(Qb, Kb, Vtb, attnb);

  // out = attn @ wo^T  (2048 x 5120 x 8192), f32 output
  gemm_bt<1><<<dim3(16, 40), 256, 0, stream>>>(attnb, Wb, (float*)d_out, 2048, 5120, 8192);
}

// Round 6
// 819.577 us; speedup vs baseline: 1.5628x; 1.1887x over previous
//
#include <hip/hip_runtime.h>

typedef unsigned short ushort_t;
typedef __attribute__((ext_vector_type(8))) short short8;
typedef __attribute__((ext_vector_type(4))) float f32x4;
typedef __attribute__((ext_vector_type(16))) float f32x16;

#define AS1U(p) ((const __attribute__((address_space(1))) unsigned int*)(p))
#define AS3U(p) ((__attribute__((address_space(3))) unsigned int*)(p))

__device__ __forceinline__ float bf2f(ushort_t u) {
  union { unsigned int i; float f; } v; v.i = ((unsigned int)u) << 16; return v.f;
}
__device__ __forceinline__ ushort_t f2bf(float f) {
  union { float f; unsigned int i; } v; v.f = f;
  unsigned int r = v.i + 0x7fffu + ((v.i >> 16) & 1u);
  return (ushort_t)(r >> 16);
}

// pack 8 f32 (S[base..base+7]) into short8 of bf16 via cvt_pk
#define PACK8(dst, S, base)                                                             \
  {                                                                                     \
    union { unsigned int u[4]; short8 s; } pk;                                          \
    asm("v_cvt_pk_bf16_f32 %0, %1, %2" : "=v"(pk.u[0]) : "v"(S[base + 0]), "v"(S[base + 1])); \
    asm("v_cvt_pk_bf16_f32 %0, %1, %2" : "=v"(pk.u[1]) : "v"(S[base + 2]), "v"(S[base + 3])); \
    asm("v_cvt_pk_bf16_f32 %0, %1, %2" : "=v"(pk.u[2]) : "v"(S[base + 4]), "v"(S[base + 5])); \
    asm("v_cvt_pk_bf16_f32 %0, %1, %2" : "=v"(pk.u[3]) : "v"(S[base + 6]), "v"(S[base + 7])); \
    dst = pk.s;                                                                         \
  }

// -------------------- f32 -> bf16 (8 elems/thread) --------------------
__global__ void cvt_bf16(const float* __restrict__ src, ushort_t* __restrict__ dst, int n8) {
  int i = blockIdx.x * 256 + threadIdx.x;
  if (i >= n8) return;
  const float4* s4 = (const float4*)src;
  float4 a = s4[2 * i], b = s4[2 * i + 1];
  short8 u;
  u[0] = (short)f2bf(a.x); u[1] = (short)f2bf(a.y); u[2] = (short)f2bf(a.z); u[3] = (short)f2bf(a.w);
  u[4] = (short)f2bf(b.x); u[5] = (short)f2bf(b.y); u[6] = (short)f2bf(b.z); u[7] = (short)f2bf(b.w);
  *(short8*)(dst + (size_t)i * 8) = u;
}

// -------------------- bf16 GEMM: C[M][N] = A[M][K] * B[N][K]^T --------------------
template <int OUTF32>
__global__ __launch_bounds__(256) void gemm_bt(const ushort_t* __restrict__ A,
                                               const ushort_t* __restrict__ B,
                                               void* __restrict__ Cv,
                                               int M, int N, int K) {
  __shared__ __align__(16) ushort_t As[128 * 32];
  __shared__ __align__(16) ushort_t Bs[128 * 32];
  const int t = threadIdx.x;
  const int lane = t & 63, w = t >> 6;
  const int wr = w >> 1, wc = w & 1;
  const int r = lane & 15, g = lane >> 4;
  const int nwg = gridDim.x * gridDim.y;
  const int l = blockIdx.y * gridDim.x + blockIdx.x;
  const int wg = (l & 7) * (nwg >> 3) + (l >> 3);
  const int m0 = (wg & (gridDim.x - 1)) * 128, n0 = (wg / gridDim.x) * 128;
  f32x4 acc[4][4] = {};
  for (int k0 = 0; k0 < K; k0 += 32) {
    __syncthreads();
#pragma unroll
    for (int i = 0; i < 2; ++i) {
      int slot = t + i * 256;
      int row = slot >> 2;
      int c8 = (slot & 3) * 8;
      __builtin_amdgcn_global_load_lds(AS1U(A + (size_t)(m0 + row) * K + k0 + c8),
                                       AS3U(As + slot * 8), 16, 0, 0);
      __builtin_amdgcn_global_load_lds(AS1U(B + (size_t)(n0 + row) * K + k0 + c8),
                                       AS3U(Bs + slot * 8), 16, 0, 0);
    }
    __syncthreads();
    short8 afrag[4], bfrag[4];
#pragma unroll
    for (int m = 0; m < 4; ++m)
      afrag[m] = *(const short8*)(As + (wr * 64 + m * 16 + r) * 32 + g * 8);
#pragma unroll
    for (int n = 0; n < 4; ++n)
      bfrag[n] = *(const short8*)(Bs + (wc * 64 + n * 16 + r) * 32 + g * 8);
    __builtin_amdgcn_s_setprio(1);
#pragma unroll
    for (int m = 0; m < 4; ++m)
#pragma unroll
      for (int n = 0; n < 4; ++n)
        acc[m][n] = __builtin_amdgcn_mfma_f32_16x16x32_bf16(afrag[m], bfrag[n], acc[m][n], 0, 0, 0);
    __builtin_amdgcn_s_setprio(0);
  }
#pragma unroll
  for (int m = 0; m < 4; ++m)
#pragma unroll
    for (int n = 0; n < 4; ++n)
#pragma unroll
      for (int j = 0; j < 4; ++j) {
        int row = m0 + wr * 64 + m * 16 + g * 4 + j;
        int col = n0 + wc * 64 + n * 16 + r;
        if (OUTF32)
          ((float*)Cv)[(size_t)row * N + col] = acc[m][n][j];
        else
          ((ushort_t*)Cv)[(size_t)row * N + col] = f2bf(acc[m][n][j]);
      }
}

// -------------------- fused RMSNorm + RoPE + head split --------------------
__global__ void normrope(const ushort_t* __restrict__ qkv,
                         const float* __restrict__ qw, const float* __restrict__ kw,
                         const float* __restrict__ fc, const float* __restrict__ fs,
                         ushort_t* __restrict__ Qb, ushort_t* __restrict__ Kb) {
  const int slot = blockIdx.x, s = blockIdx.y, t = threadIdx.x;
  const ushort_t* src;
  ushort_t* dst;
  const float* wn;
  float scale = 1.0f;
  if (slot < 64) {
    src = qkv + (size_t)s * 10240 + slot * 128;
    dst = Qb + ((size_t)slot * 2048 + s) * 128;
    wn = qw;
    scale = 0.08838834764831845f;  // 1/sqrt(128) folded into Q
  } else {
    int kh = slot - 64;
    src = qkv + (size_t)s * 10240 + 8192 + kh * 128;
    dst = Kb + ((size_t)kh * 2048 + s) * 128;
    wn = kw;
  }
  float e0 = bf2f(src[2 * t]), e1 = bf2f(src[2 * t + 1]);
  float ss = e0 * e0 + e1 * e1;
#pragma unroll
  for (int m = 1; m < 64; m <<= 1) ss += __shfl_xor(ss, m);
  float rn = rsqrtf(ss * (1.0f / 128.0f) + 1e-6f);
  float v0 = e0 * rn * wn[2 * t], v1 = e1 * rn * wn[2 * t + 1];
  float c = fc[s * 64 + t], sn = fs[s * 64 + t];
  float oe = v0 * c - v1 * sn;
  float oo = v0 * sn + v1 * c;
  dst[2 * t] = f2bf(oe * scale);
  dst[2 * t + 1] = f2bf(oo * scale);
}

// -------------------- V transpose: qkv V-section [s][kvh*128+d] -> Vt[kvh][d][s] --------------------
__global__ __launch_bounds__(256) void vtrans(const ushort_t* __restrict__ qkv,
                                              ushort_t* __restrict__ Vt) {
  __shared__ __align__(16) ushort_t T[64 * 128];
  const int t = threadIdx.x, st = blockIdx.x, kvh = blockIdx.y;
#pragma unroll
  for (int i = 0; i < 4; ++i) {
    int slot = t + i * 256;
    int srow = slot >> 4, c8 = slot & 15;
    short8 v = *(const short8*)(qkv + (size_t)(st * 64 + srow) * 10240 + 9216 + kvh * 128 + c8 * 8);
    int sw = (((srow & 7) ^ ((srow >> 3) & 7)) << 4);
    *(short8*)((char*)T + srow * 256 + ((c8 * 16) ^ sw)) = v;
  }
  __syncthreads();
#pragma unroll
  for (int i = 0; i < 4; ++i) {
    int slot = t + i * 256;
    int d = slot >> 3, s8 = slot & 7;
    short8 u;
#pragma unroll
    for (int j = 0; j < 8; ++j) {
      int row = s8 * 8 + j;
      int sw = (((row & 7) ^ ((row >> 3) & 7)) << 4);
      u[j] = *(const ushort_t*)((char*)T + row * 256 + ((d * 2) ^ sw));
    }
    *(short8*)(Vt + ((size_t)kvh * 128 + d) * 2048 + st * 64 + s8 * 8) = u;
  }
}

// -------------------- causal flash attention (GQA 8:1), swapped-QK^T 32x32 --------------------
// grid (64 heads, 16 qtiles reversed), block 256 (4 waves). Wave: 32 q rows. KV tile 64.
// S^T = mfma(K_perm, Q): A rows fed permuted so lane (hi,q5) register r holds
// kv = (r>>3)*16 + hi*8 + (r&7) -- exactly the PV B-operand order (no cross-lane P exchange).
__global__ __launch_bounds__(256) void attn_fwd(const ushort_t* __restrict__ Qg,
                                                const ushort_t* __restrict__ Kg,
                                                const ushort_t* __restrict__ VtG,
                                                ushort_t* __restrict__ Og) {
  __shared__ __align__(16) ushort_t Ks[2][64 * 128];   // [kv][d], chunk-XOR swizzled
  __shared__ __align__(16) ushort_t Vs[2][128 * 64];   // [d][kv], chunk-XOR swizzled
  const int t = threadIdx.x, lane = t & 63, w = t >> 6;
  const int q5 = lane & 31, hi = lane >> 5;
  const int h = blockIdx.x, qt = (int)gridDim.y - 1 - (int)blockIdx.y, kvh = h >> 3;
  const int qrow0 = qt * 128 + w * 32;
  const int qglob = qrow0 + q5;

  // permuted K row for the S^T A-operand: m = q5 -> kr = g(m)
  const int pa = q5 & 3, pp = (q5 >> 2) & 1, pb = q5 >> 3;
  const int kr = (pb >> 1) * 16 + pp * 8 + (pb & 1) * 4 + pa;
  const int kswz = (kr & 7) << 4;
  const int swz = (q5 & 7) << 4;

  // Q fragments (B-operand): col q = q5, k-slice = hi*8; 8 k-steps of 16
  short8 qf[8];
#pragma unroll
  for (int ks = 0; ks < 8; ++ks)
    qf[ks] = *(const short8*)(Qg + ((size_t)h * 2048 + qglob) * 128 + ks * 16 + hi * 8);

  f32x16 o[4] = {};
  float mrun = -3.0e38f, lrun = 0.0f;

  const int kbmax_blk = 2 * qt + 1;
  const int kbmax_w = (qrow0 + 31) >> 6;

  // stage K,V tiles via global_load_lds: linear LDS dest + inverse-swizzled global source
  auto STAGE = [&](int b, int kb) {
#pragma unroll
    for (int i = 0; i < 4; ++i) {
      int slot = t + i * 256;                    // 1024 16B slots (K)
      int kv = slot >> 4, c = slot & 15;
      int csrc = c ^ (kv & 7);
      __builtin_amdgcn_global_load_lds(AS1U(Kg + ((size_t)kvh * 2048 + kb * 64 + kv) * 128 + csrc * 8),
                                       AS3U(&Ks[b][0] + slot * 8), 16, 0, 0);
    }
#pragma unroll
    for (int i = 0; i < 4; ++i) {
      int slot = t + i * 256;                    // 1024 16B slots (V^T)
      int d = slot >> 3, c = slot & 7;
      int csrc = c ^ (d & 7);
      __builtin_amdgcn_global_load_lds(AS1U(VtG + ((size_t)kvh * 128 + d) * 2048 + kb * 64 + csrc * 8),
                                       AS3U(&Vs[b][0] + slot * 8), 16, 0, 0);
    }
  };

  STAGE(0, 0);
  int cur = 0;

  for (int kb = 0; kb <= kbmax_blk; ++kb) {
    asm volatile("s_waitcnt vmcnt(0)" ::: "memory");
    __syncthreads();
    if (kb < kbmax_blk) STAGE(cur ^ 1, kb + 1);

    if (kb <= kbmax_w) {
      const char* kbase = (const char*)&Ks[cur][0];
      const char* vbase = (const char*)&Vs[cur][0];

      // ---- S^T = K_perm · Q^T  (two 32-kv tiles) ----
      f32x16 st0 = {}, st1 = {};
#pragma unroll
      for (int ks = 0; ks < 8; ++ks) {
        int cslot = ((ks * 2 + hi) * 16) ^ kswz;
        short8 kf0 = *(const short8*)(kbase + kr * 256 + cslot);
        short8 kf1 = *(const short8*)(kbase + (32 + kr) * 256 + cslot);
        __builtin_amdgcn_s_setprio(1);
        st0 = __builtin_amdgcn_mfma_f32_32x32x16_bf16(kf0, qf[ks], st0, 0, 0, 0);
        st1 = __builtin_amdgcn_mfma_f32_32x32x16_bf16(kf1, qf[ks], st1, 0, 0, 0);
        __builtin_amdgcn_s_setprio(0);
      }

      // ---- causal mask (diagonal tile only); st reg r holds kv = (r>>3)*16 + hi*8 + (r&7) ----
      if (kb == kbmax_w) {
#pragma unroll
        for (int r = 0; r < 16; ++r) {
          int kv0 = kb * 64 + (r >> 3) * 16 + hi * 8 + (r & 7);
          if (kv0 > qglob) st0[r] = -1.0e30f;
          if (kv0 + 32 > qglob) st1[r] = -1.0e30f;
        }
      }

      // ---- online softmax, per-lane row (defer-max THR=8) ----
      float pmax = st0[0];
#pragma unroll
      for (int r = 1; r < 16; ++r) pmax = fmaxf(pmax, st0[r]);
#pragma unroll
      for (int r = 0; r < 16; ++r) pmax = fmaxf(pmax, st1[r]);
      pmax = fmaxf(pmax, __shfl_xor(pmax, 32));
      if (!__all(pmax <= mrun + 8.0f)) {
        float mn = fmaxf(mrun, pmax);
        float sc = __expf(mrun - mn);
        mrun = mn;
        lrun *= sc;
#pragma unroll
        for (int db = 0; db < 4; ++db) o[db] *= sc;
      }
      float rs = 0.0f;
#pragma unroll
      for (int r = 0; r < 16; ++r) { st0[r] = __expf(st0[r] - mrun); rs += st0[r]; }
#pragma unroll
      for (int r = 0; r < 16; ++r) { st1[r] = __expf(st1[r] - mrun); rs += st1[r]; }
      rs += __shfl_xor(rs, 32);
      lrun += rs;

      // ---- P -> bf16 PV fragments (register order already matches; no cross-lane) ----
      short8 pf[4];
      PACK8(pf[0], st0, 0);
      PACK8(pf[1], st0, 8);
      PACK8(pf[2], st1, 0);
      PACK8(pf[3], st1, 8);

      // ---- O^T += V^T · P^T ----
#pragma unroll
      for (int db = 0; db < 4; ++db) {
#pragma unroll
        for (int ks = 0; ks < 4; ++ks) {
          short8 vf = *(const short8*)(vbase + (db * 32 + q5) * 128 + ((((ks * 2 + hi) * 16)) ^ swz));
          __builtin_amdgcn_s_setprio(1);
          o[db] = __builtin_amdgcn_mfma_f32_32x32x16_bf16(vf, pf[ks], o[db], 0, 0, 0);
          __builtin_amdgcn_s_setprio(0);
        }
      }
    }
    cur ^= 1;
  }

  // ---- epilogue: normalize, transpose via LDS (per-wave 8KB region), coalesced store ----
  __syncthreads();
  char* tr = ((char*)Ks) + w * 8192;  // [32 q][128 d] bf16, chunk-XOR swizzled by q-row
  float inv = 1.0f / lrun;
#pragma unroll
  for (int db = 0; db < 4; ++db)
#pragma unroll
    for (int r = 0; r < 16; r += 2) {
      unsigned int u;
      float lo = o[db][r] * inv, hiv = o[db][r + 1] * inv;
      asm("v_cvt_pk_bf16_f32 %0, %1, %2" : "=v"(u) : "v"(lo), "v"(hiv));
      int d = db * 32 + (r & 3) + 8 * (r >> 2) + 4 * hi;
      *(unsigned int*)(tr + q5 * 256 + ((d * 2) ^ swz)) = u;
    }
  asm volatile("s_waitcnt lgkmcnt(0)" ::: "memory");
#pragma unroll
  for (int p = 0; p < 8; ++p) {
    int row = (lane >> 3) + (p >> 1) * 8;
    int c = (lane & 7) + (p & 1) * 8;
    // chunk at ((c*16)^sw) within row holds plain d = c*8 .. c*8+7
    short8 v = *(const short8*)(tr + row * 256 + ((c * 16) ^ ((row & 7) << 4)));
    *(short8*)(Og + (size_t)(qrow0 + row) * 8192 + h * 128 + c * 8) = v;
  }
}

// -------------------- host --------------------
extern "C" void kernel_launch(void* const* d_in, const int* in_sizes, int n_in,
                              void* d_out, int out_size, void* d_ws, size_t ws_size,
                              hipStream_t stream) {
  const float* x = (const float*)d_in[0];
  const float* wq = (const float*)d_in[1];
  const float* wk = (const float*)d_in[2];
  const float* wv = (const float*)d_in[3];
  const float* wo = (const float*)d_in[4];
  const float* qw = (const float*)d_in[5];
  const float* kw = (const float*)d_in[6];
  const float* fc = (const float*)d_in[9];
  const float* fs = (const float*)d_in[10];

  char* ws = (char*)d_ws;
  ushort_t* Wb = (ushort_t*)(ws);
  ushort_t* qkv = (ushort_t*)(ws + 104857600);
  ushort_t* xb = (ushort_t*)(ws + 146800640);
  ushort_t* Qb = xb;
  ushort_t* Kb = (ushort_t*)(ws + 180355072);
  ushort_t* Vtb = (ushort_t*)(ws + 184549376);
  ushort_t* attnb = qkv;

  {
    int n8 = 2048 * 5120 / 8;
    cvt_bf16<<<dim3((n8 + 255) / 256), 256, 0, stream>>>(x, xb, n8);
  }
  {
    int n8 = 8192 * 5120 / 8;
    cvt_bf16<<<dim3((n8 + 255) / 256), 256, 0, stream>>>(wq, Wb, n8);
  }
  {
    int n8 = 1024 * 5120 / 8;
    cvt_bf16<<<dim3((n8 + 255) / 256), 256, 0, stream>>>(wk, Wb + (size_t)8192 * 5120, n8);
    cvt_bf16<<<dim3((n8 + 255) / 256), 256, 0, stream>>>(wv, Wb + (size_t)9216 * 5120, n8);
  }

  // qkv = x @ [wq;wk;wv]^T   (2048 x 10240 x 5120)
  gemm_bt<0><<<dim3(16, 80), 256, 0, stream>>>(xb, Wb, qkv, 2048, 10240, 5120);

  // convert wo (reuses Wb region)
  {
    int n8 = 5120 * 8192 / 8;
    cvt_bf16<<<dim3((n8 + 255) / 256), 256, 0, stream>>>(wo, Wb, n8);
  }

  // rmsnorm + rope + split into head-major Q/K
  normrope<<<dim3(72, 2048), 64, 0, stream>>>(qkv, qw, kw, fc, fs, Qb, Kb);

  // V transpose: [s][kvh][d] -> [kvh][d][s]
  vtrans<<<dim3(32, 8), 256, 0, stream>>>(qkv, Vtb);

  // causal flash attention (heavy q-tiles dispatched first)
  attn_fwd<<<dim3(64, 16), 256, 0, stream>>>(Qb, Kb, Vtb, attnb);

  // out = attn @ wo^T  (2048 x 5120 x 8192), f32 output
  gemm_bt<1><<<dim3(16, 40), 256, 0, stream>>>(attnb, Wb, (float*)d_out, 2048, 5120, 8192);
}

// Round 7
// 805.672 us; speedup vs baseline: 1.5898x; 1.0173x over previous
//
#include <hip/hip_runtime.h>

typedef unsigned short ushort_t;
typedef __attribute__((ext_vector_type(8))) short short8;
typedef __attribute__((ext_vector_type(4))) float f32x4;
typedef __attribute__((ext_vector_type(16))) float f32x16;

#define AS1U(p) ((const __attribute__((address_space(1))) unsigned int*)(p))
#define AS3U(p) ((__attribute__((address_space(3))) unsigned int*)(p))

__device__ __forceinline__ float bf2f(ushort_t u) {
  union { unsigned int i; float f; } v; v.i = ((unsigned int)u) << 16; return v.f;
}
__device__ __forceinline__ ushort_t f2bf(float f) {
  union { float f; unsigned int i; } v; v.f = f;
  unsigned int r = v.i + 0x7fffu + ((v.i >> 16) & 1u);
  return (ushort_t)(r >> 16);
}

// pack 8 f32 (S[base..base+7]) into short8 of bf16 via cvt_pk
#define PACK8(dst, S, base)                                                             \
  {                                                                                     \
    union { unsigned int u[4]; short8 s; } pk;                                          \
    asm("v_cvt_pk_bf16_f32 %0, %1, %2" : "=v"(pk.u[0]) : "v"(S[base + 0]), "v"(S[base + 1])); \
    asm("v_cvt_pk_bf16_f32 %0, %1, %2" : "=v"(pk.u[1]) : "v"(S[base + 2]), "v"(S[base + 3])); \
    asm("v_cvt_pk_bf16_f32 %0, %1, %2" : "=v"(pk.u[2]) : "v"(S[base + 4]), "v"(S[base + 5])); \
    asm("v_cvt_pk_bf16_f32 %0, %1, %2" : "=v"(pk.u[3]) : "v"(S[base + 6]), "v"(S[base + 7])); \
    dst = pk.s;                                                                         \
  }

// -------------------- f32 -> bf16 (8 elems/thread) --------------------
__global__ void cvt_bf16(const float* __restrict__ src, ushort_t* __restrict__ dst, int n8) {
  int i = blockIdx.x * 256 + threadIdx.x;
  if (i >= n8) return;
  const float4* s4 = (const float4*)src;
  float4 a = s4[2 * i], b = s4[2 * i + 1];
  short8 u;
  u[0] = (short)f2bf(a.x); u[1] = (short)f2bf(a.y); u[2] = (short)f2bf(a.z); u[3] = (short)f2bf(a.w);
  u[4] = (short)f2bf(b.x); u[5] = (short)f2bf(b.y); u[6] = (short)f2bf(b.z); u[7] = (short)f2bf(b.w);
  *(short8*)(dst + (size_t)i * 8) = u;
}

// -------------------- bf16 GEMM: C[M][N] = A[M][K] * B[N][K]^T --------------------
// 128x128 tile, BK=32, 4 waves (2x2). 3-buffer LDS ring + counted vmcnt(4) (never
// drains to 0 in steady state), one raw s_barrier per K-tile, chunk-XOR LDS swizzle.
// gridDim.x must be a power of two; gridDim.x*gridDim.y must be a multiple of 8.
template <int OUTF32>
__global__ __launch_bounds__(256) void gemm3(const ushort_t* __restrict__ A,
                                             const ushort_t* __restrict__ B,
                                             void* __restrict__ Cv,
                                             int M, int N, int K) {
  __shared__ __align__(16) ushort_t SH[3][8192];  // per buf: A[128][32] | B[128][32]
  const int t = threadIdx.x;
  const int lane = t & 63, w = t >> 6;
  const int wr = w >> 1, wc = w & 1;
  const int r = lane & 15, g = lane >> 4;
  // XCD-aware bijective swizzle (nwg % 8 == 0)
  const int nwg = gridDim.x * gridDim.y;
  const int l = blockIdx.y * gridDim.x + blockIdx.x;
  const int wg = (l & 7) * (nwg >> 3) + (l >> 3);
  const int m0 = (wg & (gridDim.x - 1)) * 128, n0 = (wg / gridDim.x) * 128;
  const int NT = K >> 5;

  // stage K-tile tt into ring buffer b: linear LDS dest, inverse-swizzled global src.
  // 4 loads/thread/tile (A0,B0,A1,B1).
  auto STAGE = [&](int b, int tt) {
    const int k0 = tt * 32;
#pragma unroll
    for (int i = 0; i < 2; ++i) {
      int s = t + i * 256;               // 512 16B slots per matrix
      int row = s >> 2, c = s & 3;
      int csrc = c ^ ((row >> 1) & 3);   // involution
      __builtin_amdgcn_global_load_lds(AS1U(A + (size_t)(m0 + row) * K + k0 + csrc * 8),
                                       AS3U(&SH[b][0] + s * 8), 16, 0, 0);
      __builtin_amdgcn_global_load_lds(AS1U(B + (size_t)(n0 + row) * K + k0 + csrc * 8),
                                       AS3U(&SH[b][4096] + s * 8), 16, 0, 0);
    }
  };

  STAGE(0, 0);
  STAGE(1, 1);
  asm volatile("s_waitcnt vmcnt(4)" ::: "memory");  // tile0 complete; tile1 in flight
  __builtin_amdgcn_s_barrier();

  f32x4 acc[4][4] = {};
  int bsel = 0;
  const int cA = g ^ ((r >> 1) & 3);  // swizzled chunk for frag reads (row>>1 &3 == r>>1 &3)
  for (int tt = 0; tt < NT; ++tt) {
    const ushort_t* As = &SH[bsel][0];
    const ushort_t* Bs = &SH[bsel][4096];
    short8 af[4], bf[4];
#pragma unroll
    for (int m = 0; m < 4; ++m)
      af[m] = *(const short8*)(As + (wr * 64 + m * 16 + r) * 32 + cA * 8);
#pragma unroll
    for (int n = 0; n < 4; ++n)
      bf[n] = *(const short8*)(Bs + (wc * 64 + n * 16 + r) * 32 + cA * 8);
    int b2 = bsel + 2; if (b2 >= 3) b2 -= 3;
    const int t2 = tt + 2;
    if (t2 < NT) STAGE(b2, t2);
    __builtin_amdgcn_s_setprio(1);
#pragma unroll
    for (int m = 0; m < 4; ++m)
#pragma unroll
      for (int n = 0; n < 4; ++n)
        acc[m][n] = __builtin_amdgcn_mfma_f32_16x16x32_bf16(af[m], bf[n], acc[m][n], 0, 0, 0);
    __builtin_amdgcn_s_setprio(0);
    if (t2 < NT)
      asm volatile("s_waitcnt vmcnt(4)" ::: "memory");  // tile tt+1 landed; tt+2 in flight
    else
      asm volatile("s_waitcnt vmcnt(0)" ::: "memory");  // epilogue drain
    __builtin_amdgcn_s_barrier();
    bsel = bsel + 1 == 3 ? 0 : bsel + 1;
  }

#pragma unroll
  for (int m = 0; m < 4; ++m)
#pragma unroll
    for (int n = 0; n < 4; ++n)
#pragma unroll
      for (int j = 0; j < 4; ++j) {
        int row = m0 + wr * 64 + m * 16 + g * 4 + j;
        int col = n0 + wc * 64 + n * 16 + r;
        if (OUTF32)
          ((float*)Cv)[(size_t)row * N + col] = acc[m][n][j];
        else
          ((ushort_t*)Cv)[(size_t)row * N + col] = f2bf(acc[m][n][j]);
      }
}

// -------------------- fused RMSNorm + RoPE + head split --------------------
__global__ void normrope(const ushort_t* __restrict__ qkv,
                         const float* __restrict__ qw, const float* __restrict__ kw,
                         const float* __restrict__ fc, const float* __restrict__ fs,
                         ushort_t* __restrict__ Qb, ushort_t* __restrict__ Kb) {
  const int slot = blockIdx.x, s = blockIdx.y, t = threadIdx.x;
  const ushort_t* src;
  ushort_t* dst;
  const float* wn;
  float scale = 1.0f;
  if (slot < 64) {
    src = qkv + (size_t)s * 10240 + slot * 128;
    dst = Qb + ((size_t)slot * 2048 + s) * 128;
    wn = qw;
    scale = 0.08838834764831845f;  // 1/sqrt(128) folded into Q
  } else {
    int kh = slot - 64;
    src = qkv + (size_t)s * 10240 + 8192 + kh * 128;
    dst = Kb + ((size_t)kh * 2048 + s) * 128;
    wn = kw;
  }
  float e0 = bf2f(src[2 * t]), e1 = bf2f(src[2 * t + 1]);
  float ss = e0 * e0 + e1 * e1;
#pragma unroll
  for (int m = 1; m < 64; m <<= 1) ss += __shfl_xor(ss, m);
  float rn = rsqrtf(ss * (1.0f / 128.0f) + 1e-6f);
  float v0 = e0 * rn * wn[2 * t], v1 = e1 * rn * wn[2 * t + 1];
  float c = fc[s * 64 + t], sn = fs[s * 64 + t];
  float oe = v0 * c - v1 * sn;
  float oo = v0 * sn + v1 * c;
  dst[2 * t] = f2bf(oe * scale);
  dst[2 * t + 1] = f2bf(oo * scale);
}

// -------------------- V transpose: qkv V-section [s][kvh*128+d] -> Vt[kvh][d][s] --------------------
__global__ __launch_bounds__(256) void vtrans(const ushort_t* __restrict__ qkv,
                                              ushort_t* __restrict__ Vt) {
  __shared__ __align__(16) ushort_t T[64 * 128];
  const int t = threadIdx.x, st = blockIdx.x, kvh = blockIdx.y;
#pragma unroll
  for (int i = 0; i < 4; ++i) {
    int slot = t + i * 256;
    int srow = slot >> 4, c8 = slot & 15;
    short8 v = *(const short8*)(qkv + (size_t)(st * 64 + srow) * 10240 + 9216 + kvh * 128 + c8 * 8);
    int sw = (((srow & 7) ^ ((srow >> 3) & 7)) << 4);
    *(short8*)((char*)T + srow * 256 + ((c8 * 16) ^ sw)) = v;
  }
  __syncthreads();
#pragma unroll
  for (int i = 0; i < 4; ++i) {
    int slot = t + i * 256;
    int d = slot >> 3, s8 = slot & 7;
    short8 u;
#pragma unroll
    for (int j = 0; j < 8; ++j) {
      int row = s8 * 8 + j;
      int sw = (((row & 7) ^ ((row >> 3) & 7)) << 4);
      u[j] = *(const ushort_t*)((char*)T + row * 256 + ((d * 2) ^ sw));
    }
    *(short8*)(Vt + ((size_t)kvh * 128 + d) * 2048 + st * 64 + s8 * 8) = u;
  }
}

// -------------------- causal flash attention (GQA 8:1), swapped-QK^T 32x32 --------------------
// grid (64 heads, 16 qtiles reversed), block 256 (4 waves). Wave: 32 q rows. KV tile 64.
// S^T = mfma(K_perm, Q): A rows fed permuted so lane (hi,q5) register r holds
// kv = (r>>3)*16 + hi*8 + (r&7) -- exactly the PV B-operand order (no cross-lane P exchange).
__global__ __launch_bounds__(256) void attn_fwd(const ushort_t* __restrict__ Qg,
                                                const ushort_t* __restrict__ Kg,
                                                const ushort_t* __restrict__ VtG,
                                                ushort_t* __restrict__ Og) {
  __shared__ __align__(16) ushort_t Ks[2][64 * 128];   // [kv][d], chunk-XOR swizzled
  __shared__ __align__(16) ushort_t Vs[2][128 * 64];   // [d][kv], chunk-XOR swizzled
  const int t = threadIdx.x, lane = t & 63, w = t >> 6;
  const int q5 = lane & 31, hi = lane >> 5;
  const int h = blockIdx.x, qt = (int)gridDim.y - 1 - (int)blockIdx.y, kvh = h >> 3;
  const int qrow0 = qt * 128 + w * 32;
  const int qglob = qrow0 + q5;

  // permuted K row for the S^T A-operand: m = q5 -> kr = g(m)
  const int pa = q5 & 3, pp = (q5 >> 2) & 1, pb = q5 >> 3;
  const int kr = (pb >> 1) * 16 + pp * 8 + (pb & 1) * 4 + pa;
  const int kswz = (kr & 7) << 4;
  const int swz = (q5 & 7) << 4;

  // Q fragments (B-operand): col q = q5, k-slice = hi*8; 8 k-steps of 16
  short8 qf[8];
#pragma unroll
  for (int ks = 0; ks < 8; ++ks)
    qf[ks] = *(const short8*)(Qg + ((size_t)h * 2048 + qglob) * 128 + ks * 16 + hi * 8);

  f32x16 o[4] = {};
  float mrun = -3.0e38f, lrun = 0.0f;

  const int kbmax_blk = 2 * qt + 1;
  const int kbmax_w = (qrow0 + 31) >> 6;

  // stage K,V tiles via global_load_lds: linear LDS dest + inverse-swizzled global source
  auto STAGE = [&](int b, int kb) {
#pragma unroll
    for (int i = 0; i < 4; ++i) {
      int slot = t + i * 256;                    // 1024 16B slots (K)
      int kv = slot >> 4, c = slot & 15;
      int csrc = c ^ (kv & 7);
      __builtin_amdgcn_global_load_lds(AS1U(Kg + ((size_t)kvh * 2048 + kb * 64 + kv) * 128 + csrc * 8),
                                       AS3U(&Ks[b][0] + slot * 8), 16, 0, 0);
    }
#pragma unroll
    for (int i = 0; i < 4; ++i) {
      int slot = t + i * 256;                    // 1024 16B slots (V^T)
      int d = slot >> 3, c = slot & 7;
      int csrc = c ^ (d & 7);
      __builtin_amdgcn_global_load_lds(AS1U(VtG + ((size_t)kvh * 128 + d) * 2048 + kb * 64 + csrc * 8),
                                       AS3U(&Vs[b][0] + slot * 8), 16, 0, 0);
    }
  };

  STAGE(0, 0);
  int cur = 0;

  for (int kb = 0; kb <= kbmax_blk; ++kb) {
    asm volatile("s_waitcnt vmcnt(0)" ::: "memory");
    __syncthreads();
    if (kb < kbmax_blk) STAGE(cur ^ 1, kb + 1);

    if (kb <= kbmax_w) {
      const char* kbase = (const char*)&Ks[cur][0];
      const char* vbase = (const char*)&Vs[cur][0];

      // ---- S^T = K_perm · Q^T  (two 32-kv tiles) ----
      f32x16 st0 = {}, st1 = {};
#pragma unroll
      for (int ks = 0; ks < 8; ++ks) {
        int cslot = ((ks * 2 + hi) * 16) ^ kswz;
        short8 kf0 = *(const short8*)(kbase + kr * 256 + cslot);
        short8 kf1 = *(const short8*)(kbase + (32 + kr) * 256 + cslot);
        __builtin_amdgcn_s_setprio(1);
        st0 = __builtin_amdgcn_mfma_f32_32x32x16_bf16(kf0, qf[ks], st0, 0, 0, 0);
        st1 = __builtin_amdgcn_mfma_f32_32x32x16_bf16(kf1, qf[ks], st1, 0, 0, 0);
        __builtin_amdgcn_s_setprio(0);
      }

      // ---- causal mask (diagonal tile only); st reg r holds kv = (r>>3)*16 + hi*8 + (r&7) ----
      if (kb == kbmax_w) {
#pragma unroll
        for (int r = 0; r < 16; ++r) {
          int kv0 = kb * 64 + (r >> 3) * 16 + hi * 8 + (r & 7);
          if (kv0 > qglob) st0[r] = -1.0e30f;
          if (kv0 + 32 > qglob) st1[r] = -1.0e30f;
        }
      }

      // ---- online softmax, per-lane row (defer-max THR=8) ----
      float pmax = st0[0];
#pragma unroll
      for (int r = 1; r < 16; ++r) pmax = fmaxf(pmax, st0[r]);
#pragma unroll
      for (int r = 0; r < 16; ++r) pmax = fmaxf(pmax, st1[r]);
      pmax = fmaxf(pmax, __shfl_xor(pmax, 32));
      if (!__all(pmax <= mrun + 8.0f)) {
        float mn = fmaxf(mrun, pmax);
        float sc = __expf(mrun - mn);
        mrun = mn;
        lrun *= sc;
#pragma unroll
        for (int db = 0; db < 4; ++db) o[db] *= sc;
      }
      float rs = 0.0f;
#pragma unroll
      for (int r = 0; r < 16; ++r) { st0[r] = __expf(st0[r] - mrun); rs += st0[r]; }
#pragma unroll
      for (int r = 0; r < 16; ++r) { st1[r] = __expf(st1[r] - mrun); rs += st1[r]; }
      rs += __shfl_xor(rs, 32);
      lrun += rs;

      // ---- P -> bf16 PV fragments (register order already matches; no cross-lane) ----
      short8 pf[4];
      PACK8(pf[0], st0, 0);
      PACK8(pf[1], st0, 8);
      PACK8(pf[2], st1, 0);
      PACK8(pf[3], st1, 8);

      // ---- O^T += V^T · P^T ----
#pragma unroll
      for (int db = 0; db < 4; ++db) {
#pragma unroll
        for (int ks = 0; ks < 4; ++ks) {
          short8 vf = *(const short8*)(vbase + (db * 32 + q5) * 128 + ((((ks * 2 + hi) * 16)) ^ swz));
          __builtin_amdgcn_s_setprio(1);
          o[db] = __builtin_amdgcn_mfma_f32_32x32x16_bf16(vf, pf[ks], o[db], 0, 0, 0);
          __builtin_amdgcn_s_setprio(0);
        }
      }
    }
    cur ^= 1;
  }

  // ---- epilogue: normalize, transpose via LDS (per-wave 8KB region), coalesced store ----
  __syncthreads();
  char* tr = ((char*)Ks) + w * 8192;  // [32 q][128 d] bf16, chunk-XOR swizzled by q-row
  float inv = 1.0f / lrun;
#pragma unroll
  for (int db = 0; db < 4; ++db)
#pragma unroll
    for (int r = 0; r < 16; r += 2) {
      unsigned int u;
      float lo = o[db][r] * inv, hiv = o[db][r + 1] * inv;
      asm("v_cvt_pk_bf16_f32 %0, %1, %2" : "=v"(u) : "v"(lo), "v"(hiv));
      int d = db * 32 + (r & 3) + 8 * (r >> 2) + 4 * hi;
      *(unsigned int*)(tr + q5 * 256 + ((d * 2) ^ swz)) = u;
    }
  asm volatile("s_waitcnt lgkmcnt(0)" ::: "memory");
#pragma unroll
  for (int p = 0; p < 8; ++p) {
    int row = (lane >> 3) + (p >> 1) * 8;
    int c = (lane & 7) + (p & 1) * 8;
    // chunk at ((c*16)^sw) within row holds plain d = c*8 .. c*8+7
    short8 v = *(const short8*)(tr + row * 256 + ((c * 16) ^ ((row & 7) << 4)));
    *(short8*)(Og + (size_t)(qrow0 + row) * 8192 + h * 128 + c * 8) = v;
  }
}

// -------------------- host --------------------
extern "C" void kernel_launch(void* const* d_in, const int* in_sizes, int n_in,
                              void* d_out, int out_size, void* d_ws, size_t ws_size,
                              hipStream_t stream) {
  const float* x = (const float*)d_in[0];
  const float* wq = (const float*)d_in[1];
  const float* wk = (const float*)d_in[2];
  const float* wv = (const float*)d_in[3];
  const float* wo = (const float*)d_in[4];
  const float* qw = (const float*)d_in[5];
  const float* kw = (const float*)d_in[6];
  const float* fc = (const float*)d_in[9];
  const float* fs = (const float*)d_in[10];

  char* ws = (char*)d_ws;
  ushort_t* Wb = (ushort_t*)(ws);
  ushort_t* qkv = (ushort_t*)(ws + 104857600);
  ushort_t* xb = (ushort_t*)(ws + 146800640);
  ushort_t* Qb = xb;
  ushort_t* Kb = (ushort_t*)(ws + 180355072);
  ushort_t* Vtb = (ushort_t*)(ws + 184549376);
  ushort_t* attnb = qkv;

  {
    int n8 = 2048 * 5120 / 8;
    cvt_bf16<<<dim3((n8 + 255) / 256), 256, 0, stream>>>(x, xb, n8);
  }
  {
    int n8 = 8192 * 5120 / 8;
    cvt_bf16<<<dim3((n8 + 255) / 256), 256, 0, stream>>>(wq, Wb, n8);
  }
  {
    int n8 = 1024 * 5120 / 8;
    cvt_bf16<<<dim3((n8 + 255) / 256), 256, 0, stream>>>(wk, Wb + (size_t)8192 * 5120, n8);
    cvt_bf16<<<dim3((n8 + 255) / 256), 256, 0, stream>>>(wv, Wb + (size_t)9216 * 5120, n8);
  }

  // qkv = x @ [wq;wk;wv]^T   (2048 x 10240 x 5120)
  gemm3<0><<<dim3(16, 80), 256, 0, stream>>>(xb, Wb, qkv, 2048, 10240, 5120);

  // convert wo (reuses Wb region)
  {
    int n8 = 5120 * 8192 / 8;
    cvt_bf16<<<dim3((n8 + 255) / 256), 256, 0, stream>>>(wo, Wb, n8);
  }

  // rmsnorm + rope + split into head-major Q/K
  normrope<<<dim3(72, 2048), 64, 0, stream>>>(qkv, qw, kw, fc, fs, Qb, Kb);

  // V transpose: [s][kvh][d] -> [kvh][d][s]
  vtrans<<<dim3(32, 8), 256, 0, stream>>>(qkv, Vtb);

  // causal flash attention (heavy q-tiles dispatched first)
  attn_fwd<<<dim3(64, 16), 256, 0, stream>>>(Qb, Kb, Vtb, attnb);

  // out = attn @ wo^T  (2048 x 5120 x 8192), f32 output
  gemm3<1><<<dim3(16, 40), 256, 0, stream>>>(attnb, Wb, (float*)d_out, 2048, 5120, 8192);
}

// Round 8
// 784.627 us; speedup vs baseline: 1.6325x; 1.0268x over previous
//
#include <hip/hip_runtime.h>

typedef unsigned short ushort_t;
typedef __attribute__((ext_vector_type(8))) short short8;
typedef __attribute__((ext_vector_type(4))) float f32x4;
typedef __attribute__((ext_vector_type(16))) float f32x16;

#define AS1U(p) ((const __attribute__((address_space(1))) unsigned int*)(p))
#define AS3U(p) ((__attribute__((address_space(3))) unsigned int*)(p))

__device__ __forceinline__ float bf2f(ushort_t u) {
  union { unsigned int i; float f; } v; v.i = ((unsigned int)u) << 16; return v.f;
}
__device__ __forceinline__ ushort_t f2bf(float f) {
  union { float f; unsigned int i; } v; v.f = f;
  unsigned int r = v.i + 0x7fffu + ((v.i >> 16) & 1u);
  return (ushort_t)(r >> 16);
}

// pack 8 f32 (S[base..base+7]) into short8 of bf16 via cvt_pk
#define PACK8(dst, S, base)                                                             \
  {                                                                                     \
    union { unsigned int u[4]; short8 s; } pk;                                          \
    asm("v_cvt_pk_bf16_f32 %0, %1, %2" : "=v"(pk.u[0]) : "v"(S[base + 0]), "v"(S[base + 1])); \
    asm("v_cvt_pk_bf16_f32 %0, %1, %2" : "=v"(pk.u[1]) : "v"(S[base + 2]), "v"(S[base + 3])); \
    asm("v_cvt_pk_bf16_f32 %0, %1, %2" : "=v"(pk.u[2]) : "v"(S[base + 4]), "v"(S[base + 5])); \
    asm("v_cvt_pk_bf16_f32 %0, %1, %2" : "=v"(pk.u[3]) : "v"(S[base + 6]), "v"(S[base + 7])); \
    dst = pk.s;                                                                         \
  }

// -------------------- f32 -> bf16 (8 elems/thread) --------------------
__global__ void cvt_bf16(const float* __restrict__ src, ushort_t* __restrict__ dst, int n8) {
  int i = blockIdx.x * 256 + threadIdx.x;
  if (i >= n8) return;
  const float4* s4 = (const float4*)src;
  float4 a = s4[2 * i], b = s4[2 * i + 1];
  short8 u;
  u[0] = (short)f2bf(a.x); u[1] = (short)f2bf(a.y); u[2] = (short)f2bf(a.z); u[3] = (short)f2bf(a.w);
  u[4] = (short)f2bf(b.x); u[5] = (short)f2bf(b.y); u[6] = (short)f2bf(b.z); u[7] = (short)f2bf(b.w);
  *(short8*)(dst + (size_t)i * 8) = u;
}

// -------------------- bf16 GEMM: C[M][N] = A[M][K] * B[N][K]^T --------------------
// 128x128 tile, BK=32, 4 waves (2x2). 4-buffer LDS ring, prefetch 3 tiles ahead
// (~930 cyc >= HBM latency), steady-state wait vmcnt(8), one raw s_barrier per
// K-tile, chunk-XOR LDS swizzle (conflict-free, proven r6).
// gridDim.x must be a power of two; gridDim.x*gridDim.y must be a multiple of 8.
template <int OUTF32>
__global__ __launch_bounds__(256) void gemm3(const ushort_t* __restrict__ A,
                                             const ushort_t* __restrict__ B,
                                             void* __restrict__ Cv,
                                             int M, int N, int K) {
  __shared__ __align__(16) ushort_t SH[4][8192];  // per buf: A[128][32] | B[128][32]
  const int t = threadIdx.x;
  const int lane = t & 63, w = t >> 6;
  const int wr = w >> 1, wc = w & 1;
  const int r = lane & 15, g = lane >> 4;
  // XCD-aware bijective swizzle (nwg % 8 == 0)
  const int nwg = gridDim.x * gridDim.y;
  const int l = blockIdx.y * gridDim.x + blockIdx.x;
  const int wg = (l & 7) * (nwg >> 3) + (l >> 3);
  const int m0 = (wg & (gridDim.x - 1)) * 128, n0 = (wg / gridDim.x) * 128;
  const int NT = K >> 5;

  // stage K-tile tt into ring buffer b: linear LDS dest, inverse-swizzled global src.
  // 4 loads/thread/tile (A0,B0,A1,B1).
  auto STAGE = [&](int b, int tt) {
    const int k0 = tt * 32;
#pragma unroll
    for (int i = 0; i < 2; ++i) {
      int s = t + i * 256;               // 512 16B slots per matrix
      int row = s >> 2, c = s & 3;
      int csrc = c ^ ((row >> 1) & 3);   // involution
      __builtin_amdgcn_global_load_lds(AS1U(A + (size_t)(m0 + row) * K + k0 + csrc * 8),
                                       AS3U(&SH[b][0] + s * 8), 16, 0, 0);
      __builtin_amdgcn_global_load_lds(AS1U(B + (size_t)(n0 + row) * K + k0 + csrc * 8),
                                       AS3U(&SH[b][4096] + s * 8), 16, 0, 0);
    }
  };

  STAGE(0, 0);
  STAGE(1, 1);
  STAGE(2, 2);
  asm volatile("s_waitcnt vmcnt(8)" ::: "memory");  // tile0 complete; 1,2 in flight
  __builtin_amdgcn_s_barrier();

  f32x4 acc[4][4] = {};
  int bsel = 0;
  const int cA = g ^ ((r >> 1) & 3);  // swizzled chunk for frag reads
  for (int tt = 0; tt < NT; ++tt) {
    const ushort_t* As = &SH[bsel][0];
    const ushort_t* Bs = &SH[bsel][4096];
    short8 af[4], bf[4];
#pragma unroll
    for (int m = 0; m < 4; ++m)
      af[m] = *(const short8*)(As + (wr * 64 + m * 16 + r) * 32 + cA * 8);
#pragma unroll
    for (int n = 0; n < 4; ++n)
      bf[n] = *(const short8*)(Bs + (wc * 64 + n * 16 + r) * 32 + cA * 8);
    const int t3 = tt + 3;
    if (t3 < NT) STAGE((bsel + 3) & 3, t3);
    __builtin_amdgcn_s_setprio(1);
#pragma unroll
    for (int m = 0; m < 4; ++m)
#pragma unroll
      for (int n = 0; n < 4; ++n)
        acc[m][n] = __builtin_amdgcn_mfma_f32_16x16x32_bf16(af[m], bf[n], acc[m][n], 0, 0, 0);
    __builtin_amdgcn_s_setprio(0);
    // wait: tile tt+1 landed; deeper tiles stay in flight
    if (tt + 3 < NT)
      asm volatile("s_waitcnt vmcnt(8)" ::: "memory");
    else if (tt + 2 < NT)
      asm volatile("s_waitcnt vmcnt(4)" ::: "memory");
    else if (tt + 1 < NT)
      asm volatile("s_waitcnt vmcnt(0)" ::: "memory");
    if (tt + 1 < NT) __builtin_amdgcn_s_barrier();
    bsel = (bsel + 1) & 3;
  }

#pragma unroll
  for (int m = 0; m < 4; ++m)
#pragma unroll
    for (int n = 0; n < 4; ++n)
#pragma unroll
      for (int j = 0; j < 4; ++j) {
        int row = m0 + wr * 64 + m * 16 + g * 4 + j;
        int col = n0 + wc * 64 + n * 16 + r;
        if (OUTF32)
          ((float*)Cv)[(size_t)row * N + col] = acc[m][n][j];
        else
          ((ushort_t*)Cv)[(size_t)row * N + col] = f2bf(acc[m][n][j]);
      }
}

// -------------------- fused RMSNorm + RoPE + head split --------------------
__global__ void normrope(const ushort_t* __restrict__ qkv,
                         const float* __restrict__ qw, const float* __restrict__ kw,
                         const float* __restrict__ fc, const float* __restrict__ fs,
                         ushort_t* __restrict__ Qb, ushort_t* __restrict__ Kb) {
  const int slot = blockIdx.x, s = blockIdx.y, t = threadIdx.x;
  const ushort_t* src;
  ushort_t* dst;
  const float* wn;
  float scale = 1.0f;
  if (slot < 64) {
    src = qkv + (size_t)s * 10240 + slot * 128;
    dst = Qb + ((size_t)slot * 2048 + s) * 128;
    wn = qw;
    scale = 0.08838834764831845f;  // 1/sqrt(128) folded into Q
  } else {
    int kh = slot - 64;
    src = qkv + (size_t)s * 10240 + 8192 + kh * 128;
    dst = Kb + ((size_t)kh * 2048 + s) * 128;
    wn = kw;
  }
  float e0 = bf2f(src[2 * t]), e1 = bf2f(src[2 * t + 1]);
  float ss = e0 * e0 + e1 * e1;
#pragma unroll
  for (int m = 1; m < 64; m <<= 1) ss += __shfl_xor(ss, m);
  float rn = rsqrtf(ss * (1.0f / 128.0f) + 1e-6f);
  float v0 = e0 * rn * wn[2 * t], v1 = e1 * rn * wn[2 * t + 1];
  float c = fc[s * 64 + t], sn = fs[s * 64 + t];
  float oe = v0 * c - v1 * sn;
  float oo = v0 * sn + v1 * c;
  dst[2 * t] = f2bf(oe * scale);
  dst[2 * t + 1] = f2bf(oo * scale);
}

// -------------------- V transpose: qkv V-section [s][kvh*128+d] -> Vt[kvh][d][s] --------------------
__global__ __launch_bounds__(256) void vtrans(const ushort_t* __restrict__ qkv,
                                              ushort_t* __restrict__ Vt) {
  __shared__ __align__(16) ushort_t T[64 * 128];
  const int t = threadIdx.x, st = blockIdx.x, kvh = blockIdx.y;
#pragma unroll
  for (int i = 0; i < 4; ++i) {
    int slot = t + i * 256;
    int srow = slot >> 4, c8 = slot & 15;
    short8 v = *(const short8*)(qkv + (size_t)(st * 64 + srow) * 10240 + 9216 + kvh * 128 + c8 * 8);
    int sw = (((srow & 7) ^ ((srow >> 3) & 7)) << 4);
    *(short8*)((char*)T + srow * 256 + ((c8 * 16) ^ sw)) = v;
  }
  __syncthreads();
#pragma unroll
  for (int i = 0; i < 4; ++i) {
    int slot = t + i * 256;
    int d = slot >> 3, s8 = slot & 7;
    short8 u;
#pragma unroll
    for (int j = 0; j < 8; ++j) {
      int row = s8 * 8 + j;
      int sw = (((row & 7) ^ ((row >> 3) & 7)) << 4);
      u[j] = *(const ushort_t*)((char*)T + row * 256 + ((d * 2) ^ sw));
    }
    *(short8*)(Vt + ((size_t)kvh * 128 + d) * 2048 + st * 64 + s8 * 8) = u;
  }
}

// -------------------- causal flash attention (GQA 8:1), swapped-QK^T 32x32 --------------------
// grid (64 heads, 16 qtiles reversed), block 256 (4 waves). Wave: 32 q rows. KV tile 64.
// S^T = mfma(K_perm, Q): A rows fed permuted so lane (hi,q5) register r holds
// kv = (r>>3)*16 + hi*8 + (r&7) -- exactly the PV B-operand order (no cross-lane P exchange).
__global__ __launch_bounds__(256) void attn_fwd(const ushort_t* __restrict__ Qg,
                                                const ushort_t* __restrict__ Kg,
                                                const ushort_t* __restrict__ VtG,
                                                ushort_t* __restrict__ Og) {
  __shared__ __align__(16) ushort_t Ks[2][64 * 128];   // [kv][d], chunk-XOR swizzled
  __shared__ __align__(16) ushort_t Vs[2][128 * 64];   // [d][kv], chunk-XOR swizzled
  const int t = threadIdx.x, lane = t & 63, w = t >> 6;
  const int q5 = lane & 31, hi = lane >> 5;
  const int h = blockIdx.x, qt = (int)gridDim.y - 1 - (int)blockIdx.y, kvh = h >> 3;
  const int qrow0 = qt * 128 + w * 32;
  const int qglob = qrow0 + q5;

  // permuted K row for the S^T A-operand: m = q5 -> kr = g(m)
  const int pa = q5 & 3, pp = (q5 >> 2) & 1, pb = q5 >> 3;
  const int kr = (pb >> 1) * 16 + pp * 8 + (pb & 1) * 4 + pa;
  const int kswz = (kr & 7) << 4;
  const int swz = (q5 & 7) << 4;

  // Q fragments (B-operand): col q = q5, k-slice = hi*8; 8 k-steps of 16
  short8 qf[8];
#pragma unroll
  for (int ks = 0; ks < 8; ++ks)
    qf[ks] = *(const short8*)(Qg + ((size_t)h * 2048 + qglob) * 128 + ks * 16 + hi * 8);

  f32x16 o[4] = {};
  float mrun = -3.0e38f, lrun = 0.0f;

  const int kbmax_blk = 2 * qt + 1;
  const int kbmax_w = (qrow0 + 31) >> 6;

  // stage K,V tiles via global_load_lds: linear LDS dest + inverse-swizzled global source
  auto STAGE = [&](int b, int kb) {
#pragma unroll
    for (int i = 0; i < 4; ++i) {
      int slot = t + i * 256;                    // 1024 16B slots (K)
      int kv = slot >> 4, c = slot & 15;
      int csrc = c ^ (kv & 7);
      __builtin_amdgcn_global_load_lds(AS1U(Kg + ((size_t)kvh * 2048 + kb * 64 + kv) * 128 + csrc * 8),
                                       AS3U(&Ks[b][0] + slot * 8), 16, 0, 0);
    }
#pragma unroll
    for (int i = 0; i < 4; ++i) {
      int slot = t + i * 256;                    // 1024 16B slots (V^T)
      int d = slot >> 3, c = slot & 7;
      int csrc = c ^ (d & 7);
      __builtin_amdgcn_global_load_lds(AS1U(VtG + ((size_t)kvh * 128 + d) * 2048 + kb * 64 + csrc * 8),
                                       AS3U(&Vs[b][0] + slot * 8), 16, 0, 0);
    }
  };

  STAGE(0, 0);
  int cur = 0;

  for (int kb = 0; kb <= kbmax_blk; ++kb) {
    asm volatile("s_waitcnt vmcnt(0)" ::: "memory");
    __syncthreads();
    if (kb < kbmax_blk) STAGE(cur ^ 1, kb + 1);

    if (kb <= kbmax_w) {
      const char* kbase = (const char*)&Ks[cur][0];
      const char* vbase = (const char*)&Vs[cur][0];

      // ---- S^T = K_perm · Q^T  (two 32-kv tiles) ----
      f32x16 st0 = {}, st1 = {};
#pragma unroll
      for (int ks = 0; ks < 8; ++ks) {
        int cslot = ((ks * 2 + hi) * 16) ^ kswz;
        short8 kf0 = *(const short8*)(kbase + kr * 256 + cslot);
        short8 kf1 = *(const short8*)(kbase + (32 + kr) * 256 + cslot);
        __builtin_amdgcn_s_setprio(1);
        st0 = __builtin_amdgcn_mfma_f32_32x32x16_bf16(kf0, qf[ks], st0, 0, 0, 0);
        st1 = __builtin_amdgcn_mfma_f32_32x32x16_bf16(kf1, qf[ks], st1, 0, 0, 0);
        __builtin_amdgcn_s_setprio(0);
      }

      // ---- causal mask (diagonal tile only); st reg r holds kv = (r>>3)*16 + hi*8 + (r&7) ----
      if (kb == kbmax_w) {
#pragma unroll
        for (int r = 0; r < 16; ++r) {
          int kv0 = kb * 64 + (r >> 3) * 16 + hi * 8 + (r & 7);
          if (kv0 > qglob) st0[r] = -1.0e30f;
          if (kv0 + 32 > qglob) st1[r] = -1.0e30f;
        }
      }

      // ---- online softmax, per-lane row (defer-max THR=8) ----
      float pmax = st0[0];
#pragma unroll
      for (int r = 1; r < 16; ++r) pmax = fmaxf(pmax, st0[r]);
#pragma unroll
      for (int r = 0; r < 16; ++r) pmax = fmaxf(pmax, st1[r]);
      pmax = fmaxf(pmax, __shfl_xor(pmax, 32));
      if (!__all(pmax <= mrun + 8.0f)) {
        float mn = fmaxf(mrun, pmax);
        float sc = __expf(mrun - mn);
        mrun = mn;
        lrun *= sc;
#pragma unroll
        for (int db = 0; db < 4; ++db) o[db] *= sc;
      }
      float rs = 0.0f;
#pragma unroll
      for (int r = 0; r < 16; ++r) { st0[r] = __expf(st0[r] - mrun); rs += st0[r]; }
#pragma unroll
      for (int r = 0; r < 16; ++r) { st1[r] = __expf(st1[r] - mrun); rs += st1[r]; }
      rs += __shfl_xor(rs, 32);
      lrun += rs;

      // ---- P -> bf16 PV fragments (register order already matches; no cross-lane) ----
      short8 pf[4];
      PACK8(pf[0], st0, 0);
      PACK8(pf[1], st0, 8);
      PACK8(pf[2], st1, 0);
      PACK8(pf[3], st1, 8);

      // ---- O^T += V^T · P^T ----
#pragma unroll
      for (int db = 0; db < 4; ++db) {
#pragma unroll
        for (int ks = 0; ks < 4; ++ks) {
          short8 vf = *(const short8*)(vbase + (db * 32 + q5) * 128 + ((((ks * 2 + hi) * 16)) ^ swz));
          __builtin_amdgcn_s_setprio(1);
          o[db] = __builtin_amdgcn_mfma_f32_32x32x16_bf16(vf, pf[ks], o[db], 0, 0, 0);
          __builtin_amdgcn_s_setprio(0);
        }
      }
    }
    cur ^= 1;
  }

  // ---- epilogue: normalize, transpose via LDS (per-wave 8KB region), coalesced store ----
  __syncthreads();
  char* tr = ((char*)Ks) + w * 8192;  // [32 q][128 d] bf16, chunk-XOR swizzled by q-row
  float inv = 1.0f / lrun;
#pragma unroll
  for (int db = 0; db < 4; ++db)
#pragma unroll
    for (int r = 0; r < 16; r += 2) {
      unsigned int u;
      float lo = o[db][r] * inv, hiv = o[db][r + 1] * inv;
      asm("v_cvt_pk_bf16_f32 %0, %1, %2" : "=v"(u) : "v"(lo), "v"(hiv));
      int d = db * 32 + (r & 3) + 8 * (r >> 2) + 4 * hi;
      *(unsigned int*)(tr + q5 * 256 + ((d * 2) ^ swz)) = u;
    }
  asm volatile("s_waitcnt lgkmcnt(0)" ::: "memory");
#pragma unroll
  for (int p = 0; p < 8; ++p) {
    int row = (lane >> 3) + (p >> 1) * 8;
    int c = (lane & 7) + (p & 1) * 8;
    // chunk at ((c*16)^sw) within row holds plain d = c*8 .. c*8+7
    short8 v = *(const short8*)(tr + row * 256 + ((c * 16) ^ ((row & 7) << 4)));
    *(short8*)(Og + (size_t)(qrow0 + row) * 8192 + h * 128 + c * 8) = v;
  }
}

// -------------------- host --------------------
extern "C" void kernel_launch(void* const* d_in, const int* in_sizes, int n_in,
                              void* d_out, int out_size, void* d_ws, size_t ws_size,
                              hipStream_t stream) {
  const float* x = (const float*)d_in[0];
  const float* wq = (const float*)d_in[1];
  const float* wk = (const float*)d_in[2];
  const float* wv = (const float*)d_in[3];
  const float* wo = (const float*)d_in[4];
  const float* qw = (const float*)d_in[5];
  const float* kw = (const float*)d_in[6];
  const float* fc = (const float*)d_in[9];
  const float* fs = (const float*)d_in[10];

  char* ws = (char*)d_ws;
  ushort_t* Wb = (ushort_t*)(ws);
  ushort_t* qkv = (ushort_t*)(ws + 104857600);
  ushort_t* xb = (ushort_t*)(ws + 146800640);
  ushort_t* Qb = xb;
  ushort_t* Kb = (ushort_t*)(ws + 180355072);
  ushort_t* Vtb = (ushort_t*)(ws + 184549376);
  ushort_t* attnb = qkv;

  {
    int n8 = 2048 * 5120 / 8;
    cvt_bf16<<<dim3((n8 + 255) / 256), 256, 0, stream>>>(x, xb, n8);
  }
  {
    int n8 = 8192 * 5120 / 8;
    cvt_bf16<<<dim3((n8 + 255) / 256), 256, 0, stream>>>(wq, Wb, n8);
  }
  {
    int n8 = 1024 * 5120 / 8;
    cvt_bf16<<<dim3((n8 + 255) / 256), 256, 0, stream>>>(wk, Wb + (size_t)8192 * 5120, n8);
    cvt_bf16<<<dim3((n8 + 255) / 256), 256, 0, stream>>>(wv, Wb + (size_t)9216 * 5120, n8);
  }

  // qkv = x @ [wq;wk;wv]^T   (2048 x 10240 x 5120)
  gemm3<0><<<dim3(16, 80), 256, 0, stream>>>(xb, Wb, qkv, 2048, 10240, 5120);

  // convert wo (reuses Wb region)
  {
    int n8 = 5120 * 8192 / 8;
    cvt_bf16<<<dim3((n8 + 255) / 256), 256, 0, stream>>>(wo, Wb, n8);
  }

  // rmsnorm + rope + split into head-major Q/K
  normrope<<<dim3(72, 2048), 64, 0, stream>>>(qkv, qw, kw, fc, fs, Qb, Kb);

  // V transpose: [s][kvh][d] -> [kvh][d][s]
  vtrans<<<dim3(32, 8), 256, 0, stream>>>(qkv, Vtb);

  // causal flash attention (heavy q-tiles dispatched first)
  attn_fwd<<<dim3(64, 16), 256, 0, stream>>>(Qb, Kb, Vtb, attnb);

  // out = attn @ wo^T  (2048 x 5120 x 8192), f32 output
  gemm3<1><<<dim3(16, 40), 256, 0, stream>>>(attnb, Wb, (float*)d_out, 2048, 5120, 8192);
}

// Round 9
// 761.763 us; speedup vs baseline: 1.6815x; 1.0300x over previous
//
#include <hip/hip_runtime.h>

typedef unsigned short ushort_t;
typedef __attribute__((ext_vector_type(8))) short short8;
typedef __attribute__((ext_vector_type(4))) float f32x4;
typedef __attribute__((ext_vector_type(16))) float f32x16;

#define AS1U(p) ((const __attribute__((address_space(1))) unsigned int*)(p))
#define AS3U(p) ((__attribute__((address_space(3))) unsigned int*)(p))

__device__ __forceinline__ float bf2f(ushort_t u) {
  union { unsigned int i; float f; } v; v.i = ((unsigned int)u) << 16; return v.f;
}
__device__ __forceinline__ ushort_t f2bf(float f) {
  union { float f; unsigned int i; } v; v.f = f;
  unsigned int r = v.i + 0x7fffu + ((v.i >> 16) & 1u);
  return (ushort_t)(r >> 16);
}

// pack 8 f32 (S[base..base+7]) into short8 of bf16 via cvt_pk
#define PACK8(dst, S, base)                                                             \
  {                                                                                     \
    union { unsigned int u[4]; short8 s; } pk;                                          \
    asm("v_cvt_pk_bf16_f32 %0, %1, %2" : "=v"(pk.u[0]) : "v"(S[base + 0]), "v"(S[base + 1])); \
    asm("v_cvt_pk_bf16_f32 %0, %1, %2" : "=v"(pk.u[1]) : "v"(S[base + 2]), "v"(S[base + 3])); \
    asm("v_cvt_pk_bf16_f32 %0, %1, %2" : "=v"(pk.u[2]) : "v"(S[base + 4]), "v"(S[base + 5])); \
    asm("v_cvt_pk_bf16_f32 %0, %1, %2" : "=v"(pk.u[3]) : "v"(S[base + 6]), "v"(S[base + 7])); \
    dst = pk.s;                                                                         \
  }

// -------------------- f32 -> bf16 (8 elems/thread) --------------------
__global__ void cvt_bf16(const float* __restrict__ src, ushort_t* __restrict__ dst, int n8) {
  int i = blockIdx.x * 256 + threadIdx.x;
  if (i >= n8) return;
  const float4* s4 = (const float4*)src;
  float4 a = s4[2 * i], b = s4[2 * i + 1];
  short8 u;
  u[0] = (short)f2bf(a.x); u[1] = (short)f2bf(a.y); u[2] = (short)f2bf(a.z); u[3] = (short)f2bf(a.w);
  u[4] = (short)f2bf(b.x); u[5] = (short)f2bf(b.y); u[6] = (short)f2bf(b.z); u[7] = (short)f2bf(b.w);
  *(short8*)(dst + (size_t)i * 8) = u;
}

// -------------------- bf16 GEMM: C[M][N] = A[M][K] * B[N][K]^T --------------------
// 256x256 tile, BK=32, 512 threads = 8 waves (2M x 4N), wave tile 128x64
// (0.375 ds_read per MFMA vs 0.5 at 128^2 -- the LDS-BW lever).
// 4-buffer LDS ring (32 KB each, 128 KB total), prefetch 3 tiles ahead,
// steady-state wait vmcnt(8), one raw s_barrier per K-tile, chunk-XOR swizzle.
// gridDim.x must be a power of two; gridDim.x*gridDim.y must be a multiple of 8.
template <int OUTF32>
__global__ __launch_bounds__(512, 2) void gemm256(const ushort_t* __restrict__ A,
                                                  const ushort_t* __restrict__ B,
                                                  void* __restrict__ Cv,
                                                  int M, int N, int K) {
  __shared__ __align__(16) ushort_t SH[4][16384];  // per buf: A[256][32] | B[256][32]
  const int t = threadIdx.x;
  const int lane = t & 63, w = t >> 6;
  const int wm = w >> 2, wn = w & 3;
  const int r = lane & 15, g = lane >> 4;
  // XCD-aware bijective swizzle (nwg % 8 == 0)
  const int nwg = gridDim.x * gridDim.y;
  const int l = blockIdx.y * gridDim.x + blockIdx.x;
  const int wg = (l & 7) * (nwg >> 3) + (l >> 3);
  const int m0 = (wg & (gridDim.x - 1)) * 256, n0 = (wg / gridDim.x) * 256;
  const int NT = K >> 5;

  // stage K-tile tt into ring buffer b: linear LDS dest, inverse-swizzled global src.
  // 4 loads/thread/tile (A x2, B x2).
  auto STAGE = [&](int b, int tt) {
    const int k0 = tt * 32;
#pragma unroll
    for (int i = 0; i < 2; ++i) {
      int s = t + i * 512;               // 1024 16B slots per matrix
      int row = s >> 2, c = s & 3;
      int csrc = c ^ ((row >> 1) & 3);   // involution
      __builtin_amdgcn_global_load_lds(AS1U(A + (size_t)(m0 + row) * K + k0 + csrc * 8),
                                       AS3U(&SH[b][0] + s * 8), 16, 0, 0);
      __builtin_amdgcn_global_load_lds(AS1U(B + (size_t)(n0 + row) * K + k0 + csrc * 8),
                                       AS3U(&SH[b][8192] + s * 8), 16, 0, 0);
    }
  };

  STAGE(0, 0);
  STAGE(1, 1);
  STAGE(2, 2);
  asm volatile("s_waitcnt vmcnt(8)" ::: "memory");  // tile0 complete; 1,2 in flight
  __builtin_amdgcn_s_barrier();

  f32x4 acc[8][4] = {};
  int bsel = 0;
  for (int tt = 0; tt < NT; ++tt) {
    const ushort_t* As = &SH[bsel][0];
    const ushort_t* Bs = &SH[bsel][8192];
    short8 af[8], bf[4];
#pragma unroll
    for (int m = 0; m < 8; ++m) {
      int row = wm * 128 + m * 16 + r;
      af[m] = *(const short8*)(As + row * 32 + (g ^ ((row >> 1) & 3)) * 8);
    }
#pragma unroll
    for (int n = 0; n < 4; ++n) {
      int row = wn * 64 + n * 16 + r;
      bf[n] = *(const short8*)(Bs + row * 32 + (g ^ ((row >> 1) & 3)) * 8);
    }
    const int t3 = tt + 3;
    if (t3 < NT) STAGE((bsel + 3) & 3, t3);
    __builtin_amdgcn_s_setprio(1);
#pragma unroll
    for (int m = 0; m < 8; ++m)
#pragma unroll
      for (int n = 0; n < 4; ++n)
        acc[m][n] = __builtin_amdgcn_mfma_f32_16x16x32_bf16(af[m], bf[n], acc[m][n], 0, 0, 0);
    __builtin_amdgcn_s_setprio(0);
    // wait: tile tt+1 landed; deeper tiles stay in flight
    if (tt + 3 < NT)
      asm volatile("s_waitcnt vmcnt(8)" ::: "memory");
    else if (tt + 2 < NT)
      asm volatile("s_waitcnt vmcnt(4)" ::: "memory");
    else if (tt + 1 < NT)
      asm volatile("s_waitcnt vmcnt(0)" ::: "memory");
    if (tt + 1 < NT) __builtin_amdgcn_s_barrier();
    bsel = (bsel + 1) & 3;
  }

#pragma unroll
  for (int m = 0; m < 8; ++m)
#pragma unroll
    for (int n = 0; n < 4; ++n)
#pragma unroll
      for (int j = 0; j < 4; ++j) {
        int row = m0 + wm * 128 + m * 16 + g * 4 + j;
        int col = n0 + wn * 64 + n * 16 + r;
        if (OUTF32)
          ((float*)Cv)[(size_t)row * N + col] = acc[m][n][j];
        else
          ((ushort_t*)Cv)[(size_t)row * N + col] = f2bf(acc[m][n][j]);
      }
}

// -------------------- fused RMSNorm + RoPE + head split --------------------
__global__ void normrope(const ushort_t* __restrict__ qkv,
                         const float* __restrict__ qw, const float* __restrict__ kw,
                         const float* __restrict__ fc, const float* __restrict__ fs,
                         ushort_t* __restrict__ Qb, ushort_t* __restrict__ Kb) {
  const int slot = blockIdx.x, s = blockIdx.y, t = threadIdx.x;
  const ushort_t* src;
  ushort_t* dst;
  const float* wn;
  float scale = 1.0f;
  if (slot < 64) {
    src = qkv + (size_t)s * 10240 + slot * 128;
    dst = Qb + ((size_t)slot * 2048 + s) * 128;
    wn = qw;
    scale = 0.08838834764831845f;  // 1/sqrt(128) folded into Q
  } else {
    int kh = slot - 64;
    src = qkv + (size_t)s * 10240 + 8192 + kh * 128;
    dst = Kb + ((size_t)kh * 2048 + s) * 128;
    wn = kw;
  }
  float e0 = bf2f(src[2 * t]), e1 = bf2f(src[2 * t + 1]);
  float ss = e0 * e0 + e1 * e1;
#pragma unroll
  for (int m = 1; m < 64; m <<= 1) ss += __shfl_xor(ss, m);
  float rn = rsqrtf(ss * (1.0f / 128.0f) + 1e-6f);
  float v0 = e0 * rn * wn[2 * t], v1 = e1 * rn * wn[2 * t + 1];
  float c = fc[s * 64 + t], sn = fs[s * 64 + t];
  float oe = v0 * c - v1 * sn;
  float oo = v0 * sn + v1 * c;
  dst[2 * t] = f2bf(oe * scale);
  dst[2 * t + 1] = f2bf(oo * scale);
}

// -------------------- V transpose: qkv V-section [s][kvh*128+d] -> Vt[kvh][d][s] --------------------
__global__ __launch_bounds__(256) void vtrans(const ushort_t* __restrict__ qkv,
                                              ushort_t* __restrict__ Vt) {
  __shared__ __align__(16) ushort_t T[64 * 128];
  const int t = threadIdx.x, st = blockIdx.x, kvh = blockIdx.y;
#pragma unroll
  for (int i = 0; i < 4; ++i) {
    int slot = t + i * 256;
    int srow = slot >> 4, c8 = slot & 15;
    short8 v = *(const short8*)(qkv + (size_t)(st * 64 + srow) * 10240 + 9216 + kvh * 128 + c8 * 8);
    int sw = (((srow & 7) ^ ((srow >> 3) & 7)) << 4);
    *(short8*)((char*)T + srow * 256 + ((c8 * 16) ^ sw)) = v;
  }
  __syncthreads();
#pragma unroll
  for (int i = 0; i < 4; ++i) {
    int slot = t + i * 256;
    int d = slot >> 3, s8 = slot & 7;
    short8 u;
#pragma unroll
    for (int j = 0; j < 8; ++j) {
      int row = s8 * 8 + j;
      int sw = (((row & 7) ^ ((row >> 3) & 7)) << 4);
      u[j] = *(const ushort_t*)((char*)T + row * 256 + ((d * 2) ^ sw));
    }
    *(short8*)(Vt + ((size_t)kvh * 128 + d) * 2048 + st * 64 + s8 * 8) = u;
  }
}

// -------------------- causal flash attention (GQA 8:1), swapped-QK^T 32x32 --------------------
// grid (64 heads, 16 qtiles reversed), block 256 (4 waves). Wave: 32 q rows. KV tile 64.
// S^T = mfma(K_perm, Q): A rows fed permuted so lane (hi,q5) register r holds
// kv = (r>>3)*16 + hi*8 + (r&7) -- exactly the PV B-operand order (no cross-lane P exchange).
__global__ __launch_bounds__(256) void attn_fwd(const ushort_t* __restrict__ Qg,
                                                const ushort_t* __restrict__ Kg,
                                                const ushort_t* __restrict__ VtG,
                                                ushort_t* __restrict__ Og) {
  __shared__ __align__(16) ushort_t Ks[2][64 * 128];   // [kv][d], chunk-XOR swizzled
  __shared__ __align__(16) ushort_t Vs[2][128 * 64];   // [d][kv], chunk-XOR swizzled
  const int t = threadIdx.x, lane = t & 63, w = t >> 6;
  const int q5 = lane & 31, hi = lane >> 5;
  const int h = blockIdx.x, qt = (int)gridDim.y - 1 - (int)blockIdx.y, kvh = h >> 3;
  const int qrow0 = qt * 128 + w * 32;
  const int qglob = qrow0 + q5;

  // permuted K row for the S^T A-operand: m = q5 -> kr = g(m)
  const int pa = q5 & 3, pp = (q5 >> 2) & 1, pb = q5 >> 3;
  const int kr = (pb >> 1) * 16 + pp * 8 + (pb & 1) * 4 + pa;
  const int kswz = (kr & 7) << 4;
  const int swz = (q5 & 7) << 4;

  // Q fragments (B-operand): col q = q5, k-slice = hi*8; 8 k-steps of 16
  short8 qf[8];
#pragma unroll
  for (int ks = 0; ks < 8; ++ks)
    qf[ks] = *(const short8*)(Qg + ((size_t)h * 2048 + qglob) * 128 + ks * 16 + hi * 8);

  f32x16 o[4] = {};
  float mrun = -3.0e38f, lrun = 0.0f;

  const int kbmax_blk = 2 * qt + 1;
  const int kbmax_w = (qrow0 + 31) >> 6;

  // stage K,V tiles via global_load_lds: linear LDS dest + inverse-swizzled global source
  auto STAGE = [&](int b, int kb) {
#pragma unroll
    for (int i = 0; i < 4; ++i) {
      int slot = t + i * 256;                    // 1024 16B slots (K)
      int kv = slot >> 4, c = slot & 15;
      int csrc = c ^ (kv & 7);
      __builtin_amdgcn_global_load_lds(AS1U(Kg + ((size_t)kvh * 2048 + kb * 64 + kv) * 128 + csrc * 8),
                                       AS3U(&Ks[b][0] + slot * 8), 16, 0, 0);
    }
#pragma unroll
    for (int i = 0; i < 4; ++i) {
      int slot = t + i * 256;                    // 1024 16B slots (V^T)
      int d = slot >> 3, c = slot & 7;
      int csrc = c ^ (d & 7);
      __builtin_amdgcn_global_load_lds(AS1U(VtG + ((size_t)kvh * 128 + d) * 2048 + kb * 64 + csrc * 8),
                                       AS3U(&Vs[b][0] + slot * 8), 16, 0, 0);
    }
  };

  STAGE(0, 0);
  int cur = 0;

  for (int kb = 0; kb <= kbmax_blk; ++kb) {
    asm volatile("s_waitcnt vmcnt(0)" ::: "memory");
    __syncthreads();
    if (kb < kbmax_blk) STAGE(cur ^ 1, kb + 1);

    if (kb <= kbmax_w) {
      const char* kbase = (const char*)&Ks[cur][0];
      const char* vbase = (const char*)&Vs[cur][0];

      // ---- S^T = K_perm · Q^T  (two 32-kv tiles) ----
      f32x16 st0 = {}, st1 = {};
#pragma unroll
      for (int ks = 0; ks < 8; ++ks) {
        int cslot = ((ks * 2 + hi) * 16) ^ kswz;
        short8 kf0 = *(const short8*)(kbase + kr * 256 + cslot);
        short8 kf1 = *(const short8*)(kbase + (32 + kr) * 256 + cslot);
        __builtin_amdgcn_s_setprio(1);
        st0 = __builtin_amdgcn_mfma_f32_32x32x16_bf16(kf0, qf[ks], st0, 0, 0, 0);
        st1 = __builtin_amdgcn_mfma_f32_32x32x16_bf16(kf1, qf[ks], st1, 0, 0, 0);
        __builtin_amdgcn_s_setprio(0);
      }

      // ---- causal mask (diagonal tile only); st reg r holds kv = (r>>3)*16 + hi*8 + (r&7) ----
      if (kb == kbmax_w) {
#pragma unroll
        for (int r = 0; r < 16; ++r) {
          int kv0 = kb * 64 + (r >> 3) * 16 + hi * 8 + (r & 7);
          if (kv0 > qglob) st0[r] = -1.0e30f;
          if (kv0 + 32 > qglob) st1[r] = -1.0e30f;
        }
      }

      // ---- online softmax, per-lane row (defer-max THR=8) ----
      float pmax = st0[0];
#pragma unroll
      for (int r = 1; r < 16; ++r) pmax = fmaxf(pmax, st0[r]);
#pragma unroll
      for (int r = 0; r < 16; ++r) pmax = fmaxf(pmax, st1[r]);
      pmax = fmaxf(pmax, __shfl_xor(pmax, 32));
      if (!__all(pmax <= mrun + 8.0f)) {
        float mn = fmaxf(mrun, pmax);
        float sc = __expf(mrun - mn);
        mrun = mn;
        lrun *= sc;
#pragma unroll
        for (int db = 0; db < 4; ++db) o[db] *= sc;
      }
      float rs = 0.0f;
#pragma unroll
      for (int r = 0; r < 16; ++r) { st0[r] = __expf(st0[r] - mrun); rs += st0[r]; }
#pragma unroll
      for (int r = 0; r < 16; ++r) { st1[r] = __expf(st1[r] - mrun); rs += st1[r]; }
      rs += __shfl_xor(rs, 32);
      lrun += rs;

      // ---- P -> bf16 PV fragments (register order already matches; no cross-lane) ----
      short8 pf[4];
      PACK8(pf[0], st0, 0);
      PACK8(pf[1], st0, 8);
      PACK8(pf[2], st1, 0);
      PACK8(pf[3], st1, 8);

      // ---- O^T += V^T · P^T ----
#pragma unroll
      for (int db = 0; db < 4; ++db) {
#pragma unroll
        for (int ks = 0; ks < 4; ++ks) {
          short8 vf = *(const short8*)(vbase + (db * 32 + q5) * 128 + ((((ks * 2 + hi) * 16)) ^ swz));
          __builtin_amdgcn_s_setprio(1);
          o[db] = __builtin_amdgcn_mfma_f32_32x32x16_bf16(vf, pf[ks], o[db], 0, 0, 0);
          __builtin_amdgcn_s_setprio(0);
        }
      }
    }
    cur ^= 1;
  }

  // ---- epilogue: normalize, transpose via LDS (per-wave 8KB region), coalesced store ----
  __syncthreads();
  char* tr = ((char*)Ks) + w * 8192;  // [32 q][128 d] bf16, chunk-XOR swizzled by q-row
  float inv = 1.0f / lrun;
#pragma unroll
  for (int db = 0; db < 4; ++db)
#pragma unroll
    for (int r = 0; r < 16; r += 2) {
      unsigned int u;
      float lo = o[db][r] * inv, hiv = o[db][r + 1] * inv;
      asm("v_cvt_pk_bf16_f32 %0, %1, %2" : "=v"(u) : "v"(lo), "v"(hiv));
      int d = db * 32 + (r & 3) + 8 * (r >> 2) + 4 * hi;
      *(unsigned int*)(tr + q5 * 256 + ((d * 2) ^ swz)) = u;
    }
  asm volatile("s_waitcnt lgkmcnt(0)" ::: "memory");
#pragma unroll
  for (int p = 0; p < 8; ++p) {
    int row = (lane >> 3) + (p >> 1) * 8;
    int c = (lane & 7) + (p & 1) * 8;
    // chunk at ((c*16)^sw) within row holds plain d = c*8 .. c*8+7
    short8 v = *(const short8*)(tr + row * 256 + ((c * 16) ^ ((row & 7) << 4)));
    *(short8*)(Og + (size_t)(qrow0 + row) * 8192 + h * 128 + c * 8) = v;
  }
}

// -------------------- host --------------------
extern "C" void kernel_launch(void* const* d_in, const int* in_sizes, int n_in,
                              void* d_out, int out_size, void* d_ws, size_t ws_size,
                              hipStream_t stream) {
  const float* x = (const float*)d_in[0];
  const float* wq = (const float*)d_in[1];
  const float* wk = (const float*)d_in[2];
  const float* wv = (const float*)d_in[3];
  const float* wo = (const float*)d_in[4];
  const float* qw = (const float*)d_in[5];
  const float* kw = (const float*)d_in[6];
  const float* fc = (const float*)d_in[9];
  const float* fs = (const float*)d_in[10];

  char* ws = (char*)d_ws;
  ushort_t* Wb = (ushort_t*)(ws);
  ushort_t* qkv = (ushort_t*)(ws + 104857600);
  ushort_t* xb = (ushort_t*)(ws + 146800640);
  ushort_t* Qb = xb;
  ushort_t* Kb = (ushort_t*)(ws + 180355072);
  ushort_t* Vtb = (ushort_t*)(ws + 184549376);
  ushort_t* attnb = qkv;

  {
    int n8 = 2048 * 5120 / 8;
    cvt_bf16<<<dim3((n8 + 255) / 256), 256, 0, stream>>>(x, xb, n8);
  }
  {
    int n8 = 8192 * 5120 / 8;
    cvt_bf16<<<dim3((n8 + 255) / 256), 256, 0, stream>>>(wq, Wb, n8);
  }
  {
    int n8 = 1024 * 5120 / 8;
    cvt_bf16<<<dim3((n8 + 255) / 256), 256, 0, stream>>>(wk, Wb + (size_t)8192 * 5120, n8);
    cvt_bf16<<<dim3((n8 + 255) / 256), 256, 0, stream>>>(wv, Wb + (size_t)9216 * 5120, n8);
  }

  // qkv = x @ [wq;wk;wv]^T   (2048 x 10240 x 5120), 256^2 tiles
  gemm256<0><<<dim3(8, 40), 512, 0, stream>>>(xb, Wb, qkv, 2048, 10240, 5120);

  // convert wo (reuses Wb region)
  {
    int n8 = 5120 * 8192 / 8;
    cvt_bf16<<<dim3((n8 + 255) / 256), 256, 0, stream>>>(wo, Wb, n8);
  }

  // rmsnorm + rope + split into head-major Q/K
  normrope<<<dim3(72, 2048), 64, 0, stream>>>(qkv, qw, kw, fc, fs, Qb, Kb);

  // V transpose: [s][kvh][d] -> [kvh][d][s]
  vtrans<<<dim3(32, 8), 256, 0, stream>>>(qkv, Vtb);

  // causal flash attention (heavy q-tiles dispatched first)
  attn_fwd<<<dim3(64, 16), 256, 0, stream>>>(Qb, Kb, Vtb, attnb);

  // out = attn @ wo^T  (2048 x 5120 x 8192), f32 output, 256^2 tiles
  gemm256<1><<<dim3(8, 20), 512, 0, stream>>>(attnb, Wb, (float*)d_out, 2048, 5120, 8192);
}

// Round 11
// 742.630 us; speedup vs baseline: 1.7248x; 1.0258x over previous
//
#include <hip/hip_runtime.h>

typedef unsigned short ushort_t;
typedef __attribute__((ext_vector_type(8))) short short8;
typedef __attribute__((ext_vector_type(4))) float f32x4;
typedef __attribute__((ext_vector_type(16))) float f32x16;

#define AS1U(p) ((const __attribute__((address_space(1))) unsigned int*)(p))
#define AS3U(p) ((__attribute__((address_space(3))) unsigned int*)(p))

__device__ __forceinline__ float bf2f(ushort_t u) {
  union { unsigned int i; float f; } v; v.i = ((unsigned int)u) << 16; return v.f;
}
__device__ __forceinline__ ushort_t f2bf(float f) {
  union { float f; unsigned int i; } v; v.f = f;
  unsigned int r = v.i + 0x7fffu + ((v.i >> 16) & 1u);
  return (ushort_t)(r >> 16);
}

// pack 8 f32 (S[base..base+7]) into short8 of bf16 via cvt_pk
#define PACK8(dst, S, base)                                                             \
  {                                                                                     \
    union { unsigned int u[4]; short8 s; } pk;                                          \
    asm("v_cvt_pk_bf16_f32 %0, %1, %2" : "=v"(pk.u[0]) : "v"(S[base + 0]), "v"(S[base + 1])); \
    asm("v_cvt_pk_bf16_f32 %0, %1, %2" : "=v"(pk.u[1]) : "v"(S[base + 2]), "v"(S[base + 3])); \
    asm("v_cvt_pk_bf16_f32 %0, %1, %2" : "=v"(pk.u[2]) : "v"(S[base + 4]), "v"(S[base + 5])); \
    asm("v_cvt_pk_bf16_f32 %0, %1, %2" : "=v"(pk.u[3]) : "v"(S[base + 6]), "v"(S[base + 7])); \
    dst = pk.s;                                                                         \
  }

// -------------------- f32 -> bf16 (8 elems/thread) --------------------
__global__ void cvt_bf16(const float* __restrict__ src, ushort_t* __restrict__ dst, int n8) {
  int i = blockIdx.x * 256 + threadIdx.x;
  if (i >= n8) return;
  const float4* s4 = (const float4*)src;
  float4 a = s4[2 * i], b = s4[2 * i + 1];
  short8 u;
  u[0] = (short)f2bf(a.x); u[1] = (short)f2bf(a.y); u[2] = (short)f2bf(a.z); u[3] = (short)f2bf(a.w);
  u[4] = (short)f2bf(b.x); u[5] = (short)f2bf(b.y); u[6] = (short)f2bf(b.z); u[7] = (short)f2bf(b.w);
  *(short8*)(dst + (size_t)i * 8) = u;
}

// -------------------- bf16 GEMM: C[M][N] = A[M][K] * B[N][K]^T --------------------
// 256x256 tile, BK=32, 512 threads = 8 waves (2M x 4N), wave tile 128x64.
// Phase-split schedule (T3): 2 phases per K-tile, each {ds_read subtile | 2 stage
// loads | barrier | setprio MFMA x16}. Ring-4 LDS (128 KB, 1 block/CU), counted
// vmcnt(8)/4/0 ladder once per K-tile (T4), chunk-XOR swizzle (T2), setprio (T5).
// gridDim.x must be a power of two; gridDim.x*gridDim.y must be a multiple of 8.
template <int OUTF32>
__global__ __launch_bounds__(512, 2) void gemm8p(const ushort_t* __restrict__ A,
                                                 const ushort_t* __restrict__ B,
                                                 void* __restrict__ Cv,
                                                 int M, int N, int K) {
  __shared__ __align__(16) ushort_t SH[4][16384];  // per buf: A[256][32] | B[256][32]
  const int t = threadIdx.x;
  const int lane = t & 63, w = t >> 6;
  const int wm = w >> 2, wn = w & 3;  // 2M x 4N wave grid
  const int r = lane & 15, g = lane >> 4;
  const int nwg = gridDim.x * gridDim.y;
  const int l = blockIdx.y * gridDim.x + blockIdx.x;
  const int wg = (l & 7) * (nwg >> 3) + (l >> 3);
  const int m0 = (wg & (gridDim.x - 1)) * 256, n0 = (wg / gridDim.x) * 256;
  const int NT = K >> 5;

  // stage one matrix (half=0: A, half=1: B) of K-tile tt into ring buf b.
  // 2 loads/thread; linear LDS dest, inverse-swizzled global source.
  auto STAGEH = [&](int b, int tt, int half) {
    const int k0 = tt * 32;
    const ushort_t* src = half ? B : A;
    const int base0 = half ? n0 : m0;
#pragma unroll
    for (int i = 0; i < 2; ++i) {
      int s = t + i * 512;               // 1024 16B slots per matrix
      int row = s >> 2, c = s & 3;
      int csrc = c ^ ((row >> 1) & 3);   // involution
      __builtin_amdgcn_global_load_lds(AS1U(src + (size_t)(base0 + row) * K + k0 + csrc * 8),
                                       AS3U(&SH[b][half * 8192] + s * 8), 16, 0, 0);
    }
  };

  // prologue: tiles 0,1,2 staged; tile0 landed, 1-2 in flight
  for (int u = 0; u < 3; ++u) { STAGEH(u, u, 0); STAGEH(u, u, 1); }
  asm volatile("s_waitcnt vmcnt(8)" ::: "memory");
  __builtin_amdgcn_s_barrier();

  f32x4 acc[8][4] = {};
  int bsel = 0;
  for (int tt = 0; tt < NT; ++tt) {
    const ushort_t* As = &SH[bsel][0];
    const ushort_t* Bs = &SH[bsel][8192];
    const int t3 = tt + 3;
    const int b3 = (bsel + 3) & 3;
    short8 bf[4], af0[4], af1[4];

    // ---- phase 0: rows 0-63 of wave tile ----
#pragma unroll
    for (int m = 0; m < 4; ++m) {
      int row = wm * 128 + m * 16 + r;
      af0[m] = *(const short8*)(As + row * 32 + (g ^ ((row >> 1) & 3)) * 8);
    }
#pragma unroll
    for (int n = 0; n < 4; ++n) {
      int row = wn * 64 + n * 16 + r;
      bf[n] = *(const short8*)(Bs + row * 32 + (g ^ ((row >> 1) & 3)) * 8);
    }
    if (t3 < NT) STAGEH(b3, t3, 0);
    __builtin_amdgcn_s_barrier();
    __builtin_amdgcn_s_setprio(1);
#pragma unroll
    for (int m = 0; m < 4; ++m)
#pragma unroll
      for (int n = 0; n < 4; ++n)
        acc[m][n] = __builtin_amdgcn_mfma_f32_16x16x32_bf16(af0[m], bf[n], acc[m][n], 0, 0, 0);
    __builtin_amdgcn_s_setprio(0);

    // ---- phase 1: rows 64-127 of wave tile ----
#pragma unroll
    for (int m = 0; m < 4; ++m) {
      int row = wm * 128 + 64 + m * 16 + r;
      af1[m] = *(const short8*)(As + row * 32 + (g ^ ((row >> 1) & 3)) * 8);
    }
    if (t3 < NT) STAGEH(b3, t3, 1);
    // boundary wait: retire tile tt+1's staging; deeper loads stay in flight
    if (tt + 3 < NT)
      asm volatile("s_waitcnt vmcnt(8)" ::: "memory");
    else if (tt + 2 < NT)
      asm volatile("s_waitcnt vmcnt(4)" ::: "memory");
    else if (tt + 1 < NT)
      asm volatile("s_waitcnt vmcnt(0)" ::: "memory");
    __builtin_amdgcn_s_barrier();
    __builtin_amdgcn_s_setprio(1);
#pragma unroll
    for (int m = 0; m < 4; ++m)
#pragma unroll
      for (int n = 0; n < 4; ++n)
        acc[4 + m][n] = __builtin_amdgcn_mfma_f32_16x16x32_bf16(af1[m], bf[n], acc[4 + m][n], 0, 0, 0);
    __builtin_amdgcn_s_setprio(0);
    bsel = (bsel + 1) & 3;
  }

#pragma unroll
  for (int m = 0; m < 8; ++m)
#pragma unroll
    for (int n = 0; n < 4; ++n)
#pragma unroll
      for (int j = 0; j < 4; ++j) {
        int row = m0 + wm * 128 + m * 16 + g * 4 + j;
        int col = n0 + wn * 64 + n * 16 + r;
        if (OUTF32)
          ((float*)Cv)[(size_t)row * N + col] = acc[m][n][j];
        else
          ((ushort_t*)Cv)[(size_t)row * N + col] = f2bf(acc[m][n][j]);
      }
}

// -------------------- fused RMSNorm + RoPE + head split --------------------
__global__ void normrope(const ushort_t* __restrict__ qkv,
                         const float* __restrict__ qw, const float* __restrict__ kw,
                         const float* __restrict__ fc, const float* __restrict__ fs,
                         ushort_t* __restrict__ Qb, ushort_t* __restrict__ Kb) {
  const int slot = blockIdx.x, s = blockIdx.y, t = threadIdx.x;
  const ushort_t* src;
  ushort_t* dst;
  const float* wn;
  float scale = 1.0f;
  if (slot < 64) {
    src = qkv + (size_t)s * 10240 + slot * 128;
    dst = Qb + ((size_t)slot * 2048 + s) * 128;
    wn = qw;
    scale = 0.08838834764831845f;  // 1/sqrt(128) folded into Q
  } else {
    int kh = slot - 64;
    src = qkv + (size_t)s * 10240 + 8192 + kh * 128;
    dst = Kb + ((size_t)kh * 2048 + s) * 128;
    wn = kw;
  }
  float e0 = bf2f(src[2 * t]), e1 = bf2f(src[2 * t + 1]);
  float ss = e0 * e0 + e1 * e1;
#pragma unroll
  for (int m = 1; m < 64; m <<= 1) ss += __shfl_xor(ss, m);
  float rn = rsqrtf(ss * (1.0f / 128.0f) + 1e-6f);
  float v0 = e0 * rn * wn[2 * t], v1 = e1 * rn * wn[2 * t + 1];
  float c = fc[s * 64 + t], sn = fs[s * 64 + t];
  float oe = v0 * c - v1 * sn;
  float oo = v0 * sn + v1 * c;
  dst[2 * t] = f2bf(oe * scale);
  dst[2 * t + 1] = f2bf(oo * scale);
}

// -------------------- V transpose: qkv V-section [s][kvh*128+d] -> Vt[kvh][d][s] --------------------
__global__ __launch_bounds__(256) void vtrans(const ushort_t* __restrict__ qkv,
                                              ushort_t* __restrict__ Vt) {
  __shared__ __align__(16) ushort_t T[64 * 128];
  const int t = threadIdx.x, st = blockIdx.x, kvh = blockIdx.y;
#pragma unroll
  for (int i = 0; i < 4; ++i) {
    int slot = t + i * 256;
    int srow = slot >> 4, c8 = slot & 15;
    short8 v = *(const short8*)(qkv + (size_t)(st * 64 + srow) * 10240 + 9216 + kvh * 128 + c8 * 8);
    int sw = (((srow & 7) ^ ((srow >> 3) & 7)) << 4);
    *(short8*)((char*)T + srow * 256 + ((c8 * 16) ^ sw)) = v;
  }
  __syncthreads();
#pragma unroll
  for (int i = 0; i < 4; ++i) {
    int slot = t + i * 256;
    int d = slot >> 3, s8 = slot & 7;
    short8 u;
#pragma unroll
    for (int j = 0; j < 8; ++j) {
      int row = s8 * 8 + j;
      int sw = (((row & 7) ^ ((row >> 3) & 7)) << 4);
      u[j] = *(const ushort_t*)((char*)T + row * 256 + ((d * 2) ^ sw));
    }
    *(short8*)(Vt + ((size_t)kvh * 128 + d) * 2048 + st * 64 + s8 * 8) = u;
  }
}

// -------------------- causal flash attention (GQA 8:1), swapped-QK^T 32x32 --------------------
// grid (64 heads, 16 qtiles reversed), block 256 (4 waves). Wave: 32 q rows. KV tile 64.
// S^T = mfma(K_perm, Q): A rows fed permuted so lane (hi,q5) register r holds
// kv = (r>>3)*16 + hi*8 + (r&7) -- exactly the PV B-operand order (no cross-lane P exchange).
__global__ __launch_bounds__(256) void attn_fwd(const ushort_t* __restrict__ Qg,
                                                const ushort_t* __restrict__ Kg,
                                                const ushort_t* __restrict__ VtG,
                                                ushort_t* __restrict__ Og) {
  __shared__ __align__(16) ushort_t Ks[2][64 * 128];   // [kv][d], chunk-XOR swizzled
  __shared__ __align__(16) ushort_t Vs[2][128 * 64];   // [d][kv], chunk-XOR swizzled
  const int t = threadIdx.x, lane = t & 63, w = t >> 6;
  const int q5 = lane & 31, hi = lane >> 5;
  const int h = blockIdx.x, qt = (int)gridDim.y - 1 - (int)blockIdx.y, kvh = h >> 3;
  const int qrow0 = qt * 128 + w * 32;
  const int qglob = qrow0 + q5;

  // permuted K row for the S^T A-operand: m = q5 -> kr = g(m)
  const int pa = q5 & 3, pp = (q5 >> 2) & 1, pb = q5 >> 3;
  const int kr = (pb >> 1) * 16 + pp * 8 + (pb & 1) * 4 + pa;
  const int kswz = (kr & 7) << 4;
  const int swz = (q5 & 7) << 4;

  // Q fragments (B-operand): col q = q5, k-slice = hi*8; 8 k-steps of 16
  short8 qf[8];
#pragma unroll
  for (int ks = 0; ks < 8; ++ks)
    qf[ks] = *(const short8*)(Qg + ((size_t)h * 2048 + qglob) * 128 + ks * 16 + hi * 8);

  f32x16 o[4] = {};
  float mrun = -3.0e38f, lrun = 0.0f;

  const int kbmax_blk = 2 * qt + 1;
  const int kbmax_w = (qrow0 + 31) >> 6;

  // stage K,V tiles via global_load_lds: linear LDS dest + inverse-swizzled global source
  auto STAGE = [&](int b, int kb) {
#pragma unroll
    for (int i = 0; i < 4; ++i) {
      int slot = t + i * 256;                    // 1024 16B slots (K)
      int kv = slot >> 4, c = slot & 15;
      int csrc = c ^ (kv & 7);
      __builtin_amdgcn_global_load_lds(AS1U(Kg + ((size_t)kvh * 2048 + kb * 64 + kv) * 128 + csrc * 8),
                                       AS3U(&Ks[b][0] + slot * 8), 16, 0, 0);
    }
#pragma unroll
    for (int i = 0; i < 4; ++i) {
      int slot = t + i * 256;                    // 1024 16B slots (V^T)
      int d = slot >> 3, c = slot & 7;
      int csrc = c ^ (d & 7);
      __builtin_amdgcn_global_load_lds(AS1U(VtG + ((size_t)kvh * 128 + d) * 2048 + kb * 64 + csrc * 8),
                                       AS3U(&Vs[b][0] + slot * 8), 16, 0, 0);
    }
  };

  STAGE(0, 0);
  int cur = 0;

  for (int kb = 0; kb <= kbmax_blk; ++kb) {
    asm volatile("s_waitcnt vmcnt(0)" ::: "memory");
    __syncthreads();
    if (kb < kbmax_blk) STAGE(cur ^ 1, kb + 1);

    if (kb <= kbmax_w) {
      const char* kbase = (const char*)&Ks[cur][0];
      const char* vbase = (const char*)&Vs[cur][0];

      // ---- S^T = K_perm · Q^T  (two 32-kv tiles) ----
      f32x16 st0 = {}, st1 = {};
#pragma unroll
      for (int ks = 0; ks < 8; ++ks) {
        int cslot = ((ks * 2 + hi) * 16) ^ kswz;
        short8 kf0 = *(const short8*)(kbase + kr * 256 + cslot);
        short8 kf1 = *(const short8*)(kbase + (32 + kr) * 256 + cslot);
        __builtin_amdgcn_s_setprio(1);
        st0 = __builtin_amdgcn_mfma_f32_32x32x16_bf16(kf0, qf[ks], st0, 0, 0, 0);
        st1 = __builtin_amdgcn_mfma_f32_32x32x16_bf16(kf1, qf[ks], st1, 0, 0, 0);
        __builtin_amdgcn_s_setprio(0);
      }

      // ---- causal mask (diagonal tile only); st reg r holds kv = (r>>3)*16 + hi*8 + (r&7) ----
      if (kb == kbmax_w) {
#pragma unroll
        for (int r = 0; r < 16; ++r) {
          int kv0 = kb * 64 + (r >> 3) * 16 + hi * 8 + (r & 7);
          if (kv0 > qglob) st0[r] = -1.0e30f;
          if (kv0 + 32 > qglob) st1[r] = -1.0e30f;
        }
      }

      // ---- online softmax, per-lane row (defer-max THR=8) ----
      float pmax = st0[0];
#pragma unroll
      for (int r = 1; r < 16; ++r) pmax = fmaxf(pmax, st0[r]);
#pragma unroll
      for (int r = 0; r < 16; ++r) pmax = fmaxf(pmax, st1[r]);
      pmax = fmaxf(pmax, __shfl_xor(pmax, 32));
      if (!__all(pmax <= mrun + 8.0f)) {
        float mn = fmaxf(mrun, pmax);
        float sc = __expf(mrun - mn);
        mrun = mn;
        lrun *= sc;
#pragma unroll
        for (int db = 0; db < 4; ++db) o[db] *= sc;
      }
      float rs = 0.0f;
#pragma unroll
      for (int r = 0; r < 16; ++r) { st0[r] = __expf(st0[r] - mrun); rs += st0[r]; }
#pragma unroll
      for (int r = 0; r < 16; ++r) { st1[r] = __expf(st1[r] - mrun); rs += st1[r]; }
      rs += __shfl_xor(rs, 32);
      lrun += rs;

      // ---- P -> bf16 PV fragments (register order already matches; no cross-lane) ----
      short8 pf[4];
      PACK8(pf[0], st0, 0);
      PACK8(pf[1], st0, 8);
      PACK8(pf[2], st1, 0);
      PACK8(pf[3], st1, 8);

      // ---- O^T += V^T · P^T ----
#pragma unroll
      for (int db = 0; db < 4; ++db) {
#pragma unroll
        for (int ks = 0; ks < 4; ++ks) {
          short8 vf = *(const short8*)(vbase + (db * 32 + q5) * 128 + ((((ks * 2 + hi) * 16)) ^ swz));
          __builtin_amdgcn_s_setprio(1);
          o[db] = __builtin_amdgcn_mfma_f32_32x32x16_bf16(vf, pf[ks], o[db], 0, 0, 0);
          __builtin_amdgcn_s_setprio(0);
        }
      }
    }
    cur ^= 1;
  }

  // ---- epilogue: normalize, transpose via LDS (per-wave 8KB region), coalesced store ----
  __syncthreads();
  char* tr = ((char*)Ks) + w * 8192;  // [32 q][128 d] bf16, chunk-XOR swizzled by q-row
  float inv = 1.0f / lrun;
#pragma unroll
  for (int db = 0; db < 4; ++db)
#pragma unroll
    for (int r = 0; r < 16; r += 2) {
      unsigned int u;
      float lo = o[db][r] * inv, hiv = o[db][r + 1] * inv;
      asm("v_cvt_pk_bf16_f32 %0, %1, %2" : "=v"(u) : "v"(lo), "v"(hiv));
      int d = db * 32 + (r & 3) + 8 * (r >> 2) + 4 * hi;
      *(unsigned int*)(tr + q5 * 256 + ((d * 2) ^ swz)) = u;
    }
  asm volatile("s_waitcnt lgkmcnt(0)" ::: "memory");
#pragma unroll
  for (int p = 0; p < 8; ++p) {
    int row = (lane >> 3) + (p >> 1) * 8;
    int c = (lane & 7) + (p & 1) * 8;
    // chunk at ((c*16)^sw) within row holds plain d = c*8 .. c*8+7
    short8 v = *(const short8*)(tr + row * 256 + ((c * 16) ^ ((row & 7) << 4)));
    *(short8*)(Og + (size_t)(qrow0 + row) * 8192 + h * 128 + c * 8) = v;
  }
}

// -------------------- host --------------------
extern "C" void kernel_launch(void* const* d_in, const int* in_sizes, int n_in,
                              void* d_out, int out_size, void* d_ws, size_t ws_size,
                              hipStream_t stream) {
  const float* x = (const float*)d_in[0];
  const float* wq = (const float*)d_in[1];
  const float* wk = (const float*)d_in[2];
  const float* wv = (const float*)d_in[3];
  const float* wo = (const float*)d_in[4];
  const float* qw = (const float*)d_in[5];
  const float* kw = (const float*)d_in[6];
  const float* fc = (const float*)d_in[9];
  const float* fs = (const float*)d_in[10];

  char* ws = (char*)d_ws;
  ushort_t* Wb = (ushort_t*)(ws);
  ushort_t* qkv = (ushort_t*)(ws + 104857600);
  ushort_t* xb = (ushort_t*)(ws + 146800640);
  ushort_t* Qb = xb;
  ushort_t* Kb = (ushort_t*)(ws + 180355072);
  ushort_t* Vtb = (ushort_t*)(ws + 184549376);
  ushort_t* attnb = qkv;

  {
    int n8 = 2048 * 5120 / 8;
    cvt_bf16<<<dim3((n8 + 255) / 256), 256, 0, stream>>>(x, xb, n8);
  }
  {
    int n8 = 8192 * 5120 / 8;
    cvt_bf16<<<dim3((n8 + 255) / 256), 256, 0, stream>>>(wq, Wb, n8);
  }
  {
    int n8 = 1024 * 5120 / 8;
    cvt_bf16<<<dim3((n8 + 255) / 256), 256, 0, stream>>>(wk, Wb + (size_t)8192 * 5120, n8);
    cvt_bf16<<<dim3((n8 + 255) / 256), 256, 0, stream>>>(wv, Wb + (size_t)9216 * 5120, n8);
  }

  // qkv = x @ [wq;wk;wv]^T   (2048 x 10240 x 5120), 256^2 tiles, 8-wave phase-split
  gemm8p<0><<<dim3(8, 40), 512, 0, stream>>>(xb, Wb, qkv, 2048, 10240, 5120);

  // convert wo (reuses Wb region)
  {
    int n8 = 5120 * 8192 / 8;
    cvt_bf16<<<dim3((n8 + 255) / 256), 256, 0, stream>>>(wo, Wb, n8);
  }

  // rmsnorm + rope + split into head-major Q/K
  normrope<<<dim3(72, 2048), 64, 0, stream>>>(qkv, qw, kw, fc, fs, Qb, Kb);

  // V transpose: [s][kvh][d] -> [kvh][d][s]
  vtrans<<<dim3(32, 8), 256, 0, stream>>>(qkv, Vtb);

  // causal flash attention (heavy q-tiles dispatched first)
  attn_fwd<<<dim3(64, 16), 256, 0, stream>>>(Qb, Kb, Vtb, attnb);

  // out = attn @ wo^T  (2048 x 5120 x 8192), f32 output
  gemm8p<1><<<dim3(8, 20), 512, 0, stream>>>(attnb, Wb, (float*)d_out, 2048, 5120, 8192);
}

// Round 12
// 656.048 us; speedup vs baseline: 1.9524x; 1.1320x over previous
//
#include <hip/hip_runtime.h>

typedef unsigned short ushort_t;
typedef __attribute__((ext_vector_type(8))) short short8;
typedef __attribute__((ext_vector_type(4))) float f32x4;
typedef __attribute__((ext_vector_type(16))) float f32x16;

#define AS1U(p) ((const __attribute__((address_space(1))) unsigned int*)(p))
#define AS3U(p) ((__attribute__((address_space(3))) unsigned int*)(p))

__device__ __forceinline__ float bf2f(ushort_t u) {
  union { unsigned int i; float f; } v; v.i = ((unsigned int)u) << 16; return v.f;
}
__device__ __forceinline__ ushort_t f2bf(float f) {
  union { float f; unsigned int i; } v; v.f = f;
  unsigned int r = v.i + 0x7fffu + ((v.i >> 16) & 1u);
  return (ushort_t)(r >> 16);
}

template <int N>
__device__ __forceinline__ void waitvm() {
  if constexpr (N == 0) asm volatile("s_waitcnt vmcnt(0)" ::: "memory");
  else if constexpr (N == 2) asm volatile("s_waitcnt vmcnt(2)" ::: "memory");
  else if constexpr (N == 4) asm volatile("s_waitcnt vmcnt(4)" ::: "memory");
  else if constexpr (N == 5) asm volatile("s_waitcnt vmcnt(5)" ::: "memory");
  else if constexpr (N == 8) asm volatile("s_waitcnt vmcnt(8)" ::: "memory");
  else if constexpr (N == 10) asm volatile("s_waitcnt vmcnt(10)" ::: "memory");
}

// pack 8 f32 (S[base..base+7]) into short8 of bf16 via cvt_pk
#define PACK8(dst, S, base)                                                             \
  {                                                                                     \
    union { unsigned int u[4]; short8 s; } pk;                                          \
    asm("v_cvt_pk_bf16_f32 %0, %1, %2" : "=v"(pk.u[0]) : "v"(S[base + 0]), "v"(S[base + 1])); \
    asm("v_cvt_pk_bf16_f32 %0, %1, %2" : "=v"(pk.u[1]) : "v"(S[base + 2]), "v"(S[base + 3])); \
    asm("v_cvt_pk_bf16_f32 %0, %1, %2" : "=v"(pk.u[2]) : "v"(S[base + 4]), "v"(S[base + 5])); \
    asm("v_cvt_pk_bf16_f32 %0, %1, %2" : "=v"(pk.u[3]) : "v"(S[base + 6]), "v"(S[base + 7])); \
    dst = pk.s;                                                                         \
  }

// -------------------- f32 -> bf16 (8 elems/thread) --------------------
__global__ void cvt_bf16(const float* __restrict__ src, ushort_t* __restrict__ dst, int n8) {
  int i = blockIdx.x * 256 + threadIdx.x;
  if (i >= n8) return;
  const float4* s4 = (const float4*)src;
  float4 a = s4[2 * i], b = s4[2 * i + 1];
  short8 u;
  u[0] = (short)f2bf(a.x); u[1] = (short)f2bf(a.y); u[2] = (short)f2bf(a.z); u[3] = (short)f2bf(a.w);
  u[4] = (short)f2bf(b.x); u[5] = (short)f2bf(b.y); u[6] = (short)f2bf(b.z); u[7] = (short)f2bf(b.w);
  *(short8*)(dst + (size_t)i * 8) = u;
}

// -------------------- bf16 GEMM: C[M][N] = A[M][K] * B[N][K]^T --------------------
// Tile BM x BN = (MF*32) x (NF*64), BK=32, 512 threads = 8 waves (2M x 4N),
// wave tile (MF*16) x (NF*16). Grid sized to EXACTLY 256 blocks (1/CU, no tail).
// Role-split staging: waves 0-3 stage A (LA loads), waves 4-7 stage B (LB loads);
// per-role counted vmcnt ladder. Ring-4 LDS, phase-split (2 phases/K-tile),
// chunk-XOR swizzle, setprio around MFMA clusters.
// gridDim.x must be a power of two; gridDim.x*gridDim.y must be a multiple of 8.
template <int OUTF32, int MF, int NF>
__global__ __launch_bounds__(512, 2) void gemm8p(const ushort_t* __restrict__ A,
                                                 const ushort_t* __restrict__ B,
                                                 void* __restrict__ Cv,
                                                 int M, int N, int K) {
  constexpr int BM = MF * 32, BN = NF * 64;
  constexpr int LA = BM / 64, LB = BN / 64;          // loads/thread/tile per role
  constexpr int ABUF = BM * 32;                      // elems; B region offset
  __shared__ __align__(16) ushort_t SH[4][(BM + BN) * 32];
  const int t = threadIdx.x;
  const int lane = t & 63, w = t >> 6;
  const int wm = w >> 2, wn = w & 3;  // 2M x 4N wave grid
  const int r = lane & 15, g = lane >> 4;
  const int nwg = gridDim.x * gridDim.y;
  const int l = blockIdx.y * gridDim.x + blockIdx.x;
  const int wg = (l & 7) * (nwg >> 3) + (l >> 3);
  const int m0 = (wg & (gridDim.x - 1)) * BM, n0 = (wg / gridDim.x) * BN;
  const int NT = K >> 5;
  const int t256 = t & 255;

  // stage K-tile tt into ring buf b (role-split by wave group).
  auto STAGE = [&](int b, int tt) {
    const int k0 = tt * 32;
    if (w < 4) {
#pragma unroll
      for (int i = 0; i < LA; ++i) {
        int s = t256 + i * 256;
        int row = s >> 2, c = s & 3;
        int csrc = c ^ ((row >> 1) & 3);
        __builtin_amdgcn_global_load_lds(AS1U(A + (size_t)(m0 + row) * K + k0 + csrc * 8),
                                         AS3U(&SH[b][0] + s * 8), 16, 0, 0);
      }
    } else {
#pragma unroll
      for (int i = 0; i < LB; ++i) {
        int s = t256 + i * 256;
        int row = s >> 2, c = s & 3;
        int csrc = c ^ ((row >> 1) & 3);
        __builtin_amdgcn_global_load_lds(AS1U(B + (size_t)(n0 + row) * K + k0 + csrc * 8),
                                         AS3U(&SH[b][ABUF] + s * 8), 16, 0, 0);
      }
    }
  };

  // prologue: tiles 0,1,2 staged; tile0 landed, 1-2 in flight
  STAGE(0, 0); STAGE(1, 1); STAGE(2, 2);
  if (w < 4) waitvm<2 * LA>(); else waitvm<2 * LB>();
  __builtin_amdgcn_s_barrier();

  f32x4 acc[MF][NF] = {};
  int bsel = 0;
  for (int tt = 0; tt < NT; ++tt) {
    const ushort_t* As = &SH[bsel][0];
    const ushort_t* Bs = &SH[bsel][ABUF];
    const int t3 = tt + 3;
    const int b3 = (bsel + 3) & 3;
    short8 bf[NF], af0[MF / 2], af1[MF / 2];

    // ---- phase 0: first half of wave's A rows + all B ----
#pragma unroll
    for (int m = 0; m < MF / 2; ++m) {
      int row = wm * (MF * 16) + m * 16 + r;
      af0[m] = *(const short8*)(As + row * 32 + (g ^ ((row >> 1) & 3)) * 8);
    }
#pragma unroll
    for (int n = 0; n < NF; ++n) {
      int row = wn * (NF * 16) + n * 16 + r;
      bf[n] = *(const short8*)(Bs + row * 32 + (g ^ ((row >> 1) & 3)) * 8);
    }
    if (t3 < NT) STAGE(b3, t3);
    __builtin_amdgcn_s_barrier();
    __builtin_amdgcn_s_setprio(1);
#pragma unroll
    for (int m = 0; m < MF / 2; ++m)
#pragma unroll
      for (int n = 0; n < NF; ++n)
        acc[m][n] = __builtin_amdgcn_mfma_f32_16x16x32_bf16(af0[m], bf[n], acc[m][n], 0, 0, 0);
    __builtin_amdgcn_s_setprio(0);

    // ---- phase 1: second half of wave's A rows ----
#pragma unroll
    for (int m = 0; m < MF / 2; ++m) {
      int row = wm * (MF * 16) + (MF / 2 + m) * 16 + r;
      af1[m] = *(const short8*)(As + row * 32 + (g ^ ((row >> 1) & 3)) * 8);
    }
    // boundary wait: retire tile tt+1's staging; deeper loads stay in flight
    if (tt + 3 < NT) {
      if (w < 4) waitvm<2 * LA>(); else waitvm<2 * LB>();
    } else if (tt + 2 < NT) {
      if (w < 4) waitvm<LA>(); else waitvm<LB>();
    } else if (tt + 1 < NT) {
      waitvm<0>();
    }
    __builtin_amdgcn_s_barrier();
    __builtin_amdgcn_s_setprio(1);
#pragma unroll
    for (int m = 0; m < MF / 2; ++m)
#pragma unroll
      for (int n = 0; n < NF; ++n)
        acc[MF / 2 + m][n] = __builtin_amdgcn_mfma_f32_16x16x32_bf16(af1[m], bf[n], acc[MF / 2 + m][n], 0, 0, 0);
    __builtin_amdgcn_s_setprio(0);
    bsel = (bsel + 1) & 3;
  }

#pragma unroll
  for (int m = 0; m < MF; ++m)
#pragma unroll
    for (int n = 0; n < NF; ++n)
#pragma unroll
      for (int j = 0; j < 4; ++j) {
        int row = m0 + wm * (MF * 16) + m * 16 + g * 4 + j;
        int col = n0 + wn * (NF * 16) + n * 16 + r;
        if (OUTF32)
          ((float*)Cv)[(size_t)row * N + col] = acc[m][n][j];
        else
          ((ushort_t*)Cv)[(size_t)row * N + col] = f2bf(acc[m][n][j]);
      }
}

// -------------------- fused RMSNorm + RoPE + head split --------------------
__global__ void normrope(const ushort_t* __restrict__ qkv,
                         const float* __restrict__ qw, const float* __restrict__ kw,
                         const float* __restrict__ fc, const float* __restrict__ fs,
                         ushort_t* __restrict__ Qb, ushort_t* __restrict__ Kb) {
  const int slot = blockIdx.x, s = blockIdx.y, t = threadIdx.x;
  const ushort_t* src;
  ushort_t* dst;
  const float* wn;
  float scale = 1.0f;
  if (slot < 64) {
    src = qkv + (size_t)s * 10240 + slot * 128;
    dst = Qb + ((size_t)slot * 2048 + s) * 128;
    wn = qw;
    scale = 0.08838834764831845f;  // 1/sqrt(128) folded into Q
  } else {
    int kh = slot - 64;
    src = qkv + (size_t)s * 10240 + 8192 + kh * 128;
    dst = Kb + ((size_t)kh * 2048 + s) * 128;
    wn = kw;
  }
  float e0 = bf2f(src[2 * t]), e1 = bf2f(src[2 * t + 1]);
  float ss = e0 * e0 + e1 * e1;
#pragma unroll
  for (int m = 1; m < 64; m <<= 1) ss += __shfl_xor(ss, m);
  float rn = rsqrtf(ss * (1.0f / 128.0f) + 1e-6f);
  float v0 = e0 * rn * wn[2 * t], v1 = e1 * rn * wn[2 * t + 1];
  float c = fc[s * 64 + t], sn = fs[s * 64 + t];
  float oe = v0 * c - v1 * sn;
  float oo = v0 * sn + v1 * c;
  dst[2 * t] = f2bf(oe * scale);
  dst[2 * t + 1] = f2bf(oo * scale);
}

// -------------------- V transpose: qkv V-section [s][kvh*128+d] -> Vt[kvh][d][s] --------------------
__global__ __launch_bounds__(256) void vtrans(const ushort_t* __restrict__ qkv,
                                              ushort_t* __restrict__ Vt) {
  __shared__ __align__(16) ushort_t T[64 * 128];
  const int t = threadIdx.x, st = blockIdx.x, kvh = blockIdx.y;
#pragma unroll
  for (int i = 0; i < 4; ++i) {
    int slot = t + i * 256;
    int srow = slot >> 4, c8 = slot & 15;
    short8 v = *(const short8*)(qkv + (size_t)(st * 64 + srow) * 10240 + 9216 + kvh * 128 + c8 * 8);
    int sw = (((srow & 7) ^ ((srow >> 3) & 7)) << 4);
    *(short8*)((char*)T + srow * 256 + ((c8 * 16) ^ sw)) = v;
  }
  __syncthreads();
#pragma unroll
  for (int i = 0; i < 4; ++i) {
    int slot = t + i * 256;
    int d = slot >> 3, s8 = slot & 7;
    short8 u;
#pragma unroll
    for (int j = 0; j < 8; ++j) {
      int row = s8 * 8 + j;
      int sw = (((row & 7) ^ ((row >> 3) & 7)) << 4);
      u[j] = *(const ushort_t*)((char*)T + row * 256 + ((d * 2) ^ sw));
    }
    *(short8*)(Vt + ((size_t)kvh * 128 + d) * 2048 + st * 64 + s8 * 8) = u;
  }
}

// -------------------- causal flash attention (GQA 8:1), swapped-QK^T 32x32 --------------------
// grid (64 heads, 16 qtiles reversed), block 256 (4 waves). Wave: 32 q rows. KV tile 64.
// S^T = mfma(K_perm, Q): A rows fed permuted so lane (hi,q5) register r holds
// kv = (r>>3)*16 + hi*8 + (r&7) -- exactly the PV B-operand order (no cross-lane P exchange).
__global__ __launch_bounds__(256) void attn_fwd(const ushort_t* __restrict__ Qg,
                                                const ushort_t* __restrict__ Kg,
                                                const ushort_t* __restrict__ VtG,
                                                ushort_t* __restrict__ Og) {
  __shared__ __align__(16) ushort_t Ks[2][64 * 128];   // [kv][d], chunk-XOR swizzled
  __shared__ __align__(16) ushort_t Vs[2][128 * 64];   // [d][kv], chunk-XOR swizzled
  const int t = threadIdx.x, lane = t & 63, w = t >> 6;
  const int q5 = lane & 31, hi = lane >> 5;
  const int h = blockIdx.x, qt = (int)gridDim.y - 1 - (int)blockIdx.y, kvh = h >> 3;
  const int qrow0 = qt * 128 + w * 32;
  const int qglob = qrow0 + q5;

  // permuted K row for the S^T A-operand: m = q5 -> kr = g(m)
  const int pa = q5 & 3, pp = (q5 >> 2) & 1, pb = q5 >> 3;
  const int kr = (pb >> 1) * 16 + pp * 8 + (pb & 1) * 4 + pa;
  const int kswz = (kr & 7) << 4;
  const int swz = (q5 & 7) << 4;

  // Q fragments (B-operand): col q = q5, k-slice = hi*8; 8 k-steps of 16
  short8 qf[8];
#pragma unroll
  for (int ks = 0; ks < 8; ++ks)
    qf[ks] = *(const short8*)(Qg + ((size_t)h * 2048 + qglob) * 128 + ks * 16 + hi * 8);

  f32x16 o[4] = {};
  float mrun = -3.0e38f, lrun = 0.0f;

  const int kbmax_blk = 2 * qt + 1;
  const int kbmax_w = (qrow0 + 31) >> 6;

  // stage K,V tiles via global_load_lds: linear LDS dest + inverse-swizzled global source
  auto STAGE = [&](int b, int kb) {
#pragma unroll
    for (int i = 0; i < 4; ++i) {
      int slot = t + i * 256;                    // 1024 16B slots (K)
      int kv = slot >> 4, c = slot & 15;
      int csrc = c ^ (kv & 7);
      __builtin_amdgcn_global_load_lds(AS1U(Kg + ((size_t)kvh * 2048 + kb * 64 + kv) * 128 + csrc * 8),
                                       AS3U(&Ks[b][0] + slot * 8), 16, 0, 0);
    }
#pragma unroll
    for (int i = 0; i < 4; ++i) {
      int slot = t + i * 256;                    // 1024 16B slots (V^T)
      int d = slot >> 3, c = slot & 7;
      int csrc = c ^ (d & 7);
      __builtin_amdgcn_global_load_lds(AS1U(VtG + ((size_t)kvh * 128 + d) * 2048 + kb * 64 + csrc * 8),
                                       AS3U(&Vs[b][0] + slot * 8), 16, 0, 0);
    }
  };

  STAGE(0, 0);
  int cur = 0;

  for (int kb = 0; kb <= kbmax_blk; ++kb) {
    asm volatile("s_waitcnt vmcnt(0)" ::: "memory");
    __syncthreads();
    if (kb < kbmax_blk) STAGE(cur ^ 1, kb + 1);

    if (kb <= kbmax_w) {
      const char* kbase = (const char*)&Ks[cur][0];
      const char* vbase = (const char*)&Vs[cur][0];

      // ---- S^T = K_perm · Q^T  (two 32-kv tiles) ----
      f32x16 st0 = {}, st1 = {};
#pragma unroll
      for (int ks = 0; ks < 8; ++ks) {
        int cslot = ((ks * 2 + hi) * 16) ^ kswz;
        short8 kf0 = *(const short8*)(kbase + kr * 256 + cslot);
        short8 kf1 = *(const short8*)(kbase + (32 + kr) * 256 + cslot);
        __builtin_amdgcn_s_setprio(1);
        st0 = __builtin_amdgcn_mfma_f32_32x32x16_bf16(kf0, qf[ks], st0, 0, 0, 0);
        st1 = __builtin_amdgcn_mfma_f32_32x32x16_bf16(kf1, qf[ks], st1, 0, 0, 0);
        __builtin_amdgcn_s_setprio(0);
      }

      // ---- causal mask (diagonal tile only); st reg r holds kv = (r>>3)*16 + hi*8 + (r&7) ----
      if (kb == kbmax_w) {
#pragma unroll
        for (int r = 0; r < 16; ++r) {
          int kv0 = kb * 64 + (r >> 3) * 16 + hi * 8 + (r & 7);
          if (kv0 > qglob) st0[r] = -1.0e30f;
          if (kv0 + 32 > qglob) st1[r] = -1.0e30f;
        }
      }

      // ---- online softmax, per-lane row (defer-max THR=8) ----
      float pmax = st0[0];
#pragma unroll
      for (int r = 1; r < 16; ++r) pmax = fmaxf(pmax, st0[r]);
#pragma unroll
      for (int r = 0; r < 16; ++r) pmax = fmaxf(pmax, st1[r]);
      pmax = fmaxf(pmax, __shfl_xor(pmax, 32));
      if (!__all(pmax <= mrun + 8.0f)) {
        float mn = fmaxf(mrun, pmax);
        float sc = __expf(mrun - mn);
        mrun = mn;
        lrun *= sc;
#pragma unroll
        for (int db = 0; db < 4; ++db) o[db] *= sc;
      }
      float rs = 0.0f;
#pragma unroll
      for (int r = 0; r < 16; ++r) { st0[r] = __expf(st0[r] - mrun); rs += st0[r]; }
#pragma unroll
      for (int r = 0; r < 16; ++r) { st1[r] = __expf(st1[r] - mrun); rs += st1[r]; }
      rs += __shfl_xor(rs, 32);
      lrun += rs;

      // ---- P -> bf16 PV fragments (register order already matches; no cross-lane) ----
      short8 pf[4];
      PACK8(pf[0], st0, 0);
      PACK8(pf[1], st0, 8);
      PACK8(pf[2], st1, 0);
      PACK8(pf[3], st1, 8);

      // ---- O^T += V^T · P^T ----
#pragma unroll
      for (int db = 0; db < 4; ++db) {
#pragma unroll
        for (int ks = 0; ks < 4; ++ks) {
          short8 vf = *(const short8*)(vbase + (db * 32 + q5) * 128 + ((((ks * 2 + hi) * 16)) ^ swz));
          __builtin_amdgcn_s_setprio(1);
          o[db] = __builtin_amdgcn_mfma_f32_32x32x16_bf16(vf, pf[ks], o[db], 0, 0, 0);
          __builtin_amdgcn_s_setprio(0);
        }
      }
    }
    cur ^= 1;
  }

  // ---- epilogue: normalize, transpose via LDS (per-wave 8KB region), coalesced store ----
  __syncthreads();
  char* tr = ((char*)Ks) + w * 8192;  // [32 q][128 d] bf16, chunk-XOR swizzled by q-row
  float inv = 1.0f / lrun;
#pragma unroll
  for (int db = 0; db < 4; ++db)
#pragma unroll
    for (int r = 0; r < 16; r += 2) {
      unsigned int u;
      float lo = o[db][r] * inv, hiv = o[db][r + 1] * inv;
      asm("v_cvt_pk_bf16_f32 %0, %1, %2" : "=v"(u) : "v"(lo), "v"(hiv));
      int d = db * 32 + (r & 3) + 8 * (r >> 2) + 4 * hi;
      *(unsigned int*)(tr + q5 * 256 + ((d * 2) ^ swz)) = u;
    }
  asm volatile("s_waitcnt lgkmcnt(0)" ::: "memory");
#pragma unroll
  for (int p = 0; p < 8; ++p) {
    int row = (lane >> 3) + (p >> 1) * 8;
    int c = (lane & 7) + (p & 1) * 8;
    // chunk at ((c*16)^sw) within row holds plain d = c*8 .. c*8+7
    short8 v = *(const short8*)(tr + row * 256 + ((c * 16) ^ ((row & 7) << 4)));
    *(short8*)(Og + (size_t)(qrow0 + row) * 8192 + h * 128 + c * 8) = v;
  }
}

// -------------------- host --------------------
extern "C" void kernel_launch(void* const* d_in, const int* in_sizes, int n_in,
                              void* d_out, int out_size, void* d_ws, size_t ws_size,
                              hipStream_t stream) {
  const float* x = (const float*)d_in[0];
  const float* wq = (const float*)d_in[1];
  const float* wk = (const float*)d_in[2];
  const float* wv = (const float*)d_in[3];
  const float* wo = (const float*)d_in[4];
  const float* qw = (const float*)d_in[5];
  const float* kw = (const float*)d_in[6];
  const float* fc = (const float*)d_in[9];
  const float* fs = (const float*)d_in[10];

  char* ws = (char*)d_ws;
  ushort_t* Wb = (ushort_t*)(ws);
  ushort_t* qkv = (ushort_t*)(ws + 104857600);
  ushort_t* xb = (ushort_t*)(ws + 146800640);
  ushort_t* Qb = xb;
  ushort_t* Kb = (ushort_t*)(ws + 180355072);
  ushort_t* Vtb = (ushort_t*)(ws + 184549376);
  ushort_t* attnb = qkv;

  {
    int n8 = 2048 * 5120 / 8;
    cvt_bf16<<<dim3((n8 + 255) / 256), 256, 0, stream>>>(x, xb, n8);
  }
  {
    int n8 = 8192 * 5120 / 8;
    cvt_bf16<<<dim3((n8 + 255) / 256), 256, 0, stream>>>(wq, Wb, n8);
  }
  {
    int n8 = 1024 * 5120 / 8;
    cvt_bf16<<<dim3((n8 + 255) / 256), 256, 0, stream>>>(wk, Wb + (size_t)8192 * 5120, n8);
    cvt_bf16<<<dim3((n8 + 255) / 256), 256, 0, stream>>>(wv, Wb + (size_t)9216 * 5120, n8);
  }

  // qkv = x @ [wq;wk;wv]^T   (2048 x 10240 x 5120): 256x320 tiles -> exactly 256 blocks
  gemm8p<0, 8, 5><<<dim3(8, 32), 512, 0, stream>>>(xb, Wb, qkv, 2048, 10240, 5120);

  // convert wo (reuses Wb region)
  {
    int n8 = 5120 * 8192 / 8;
    cvt_bf16<<<dim3((n8 + 255) / 256), 256, 0, stream>>>(wo, Wb, n8);
  }

  // rmsnorm + rope + split into head-major Q/K
  normrope<<<dim3(72, 2048), 64, 0, stream>>>(qkv, qw, kw, fc, fs, Qb, Kb);

  // V transpose: [s][kvh][d] -> [kvh][d][s]
  vtrans<<<dim3(32, 8), 256, 0, stream>>>(qkv, Vtb);

  // causal flash attention (heavy q-tiles dispatched first)
  attn_fwd<<<dim3(64, 16), 256, 0, stream>>>(Qb, Kb, Vtb, attnb);

  // out = attn @ wo^T  (2048 x 5120 x 8192), f32 output: 128x320 tiles -> exactly 256 blocks
  gemm8p<1, 4, 5><<<dim3(16, 16), 512, 0, stream>>>(attnb, Wb, (float*)d_out, 2048, 5120, 8192);
}